// Round 9
// baseline (373.742 us; speedup 1.0000x reference)
//
#include <hip/hip_runtime.h>
#include <hip/hip_fp16.h>
#include <math.h>

#define NN 100000
#define NE 1600000
#define RR 5
#define HH 64
#define KK 10000
#define NBB 2
#define NBK 391            // dst buckets of 256 nodes: ceil(100000/256)
#define EPB 6250           // edges per block in bucket passes (256 blocks)
#define BCAP 8192          // pass-2 LDS capacity per bucket (mean 4096, std 64)

// ---------------- h init: h[n] = emb[x[n]] (fp32 + fp16 mirror) + zero scratch ----------------
__global__ void k_init_h(const int* __restrict__ x, const float4* __restrict__ emb4,
                         float4* __restrict__ h4, unsigned short* __restrict__ hH,
                         int* __restrict__ gbcnt, int* __restrict__ bcur,
                         int* __restrict__ absorbed, float* __restrict__ denom) {
    int idx = blockIdx.x * blockDim.x + threadIdx.x;
    if (idx >= NN * 16) return;
    int n = idx >> 4;
    int q = idx & 15;
    float4 v = emb4[x[n] * 16 + q];
    h4[idx] = v;
    __half2 lo = __floats2half2_rn(v.x, v.y);
    __half2 hi = __floats2half2_rn(v.z, v.w);
    *(uint2*)&hH[(size_t)n * HH + q * 4] = make_uint2(*(unsigned*)&lo, *(unsigned*)&hi);
    // fold in scratch zeroing (completes before dependent kernels by stream order)
    if (idx < NBK) { gbcnt[idx] = 0; bcur[idx] = 0; }
    if (idx == NBK) denom[0] = 0.f;
    if (idx < NN) absorbed[idx] = 0;
}

// ---------------- PE add + absorbed mask (node_order entries distinct) ----------------
__global__ void k_pe(const int* __restrict__ order, float* __restrict__ h,
                     unsigned short* __restrict__ hH, int* __restrict__ absorbed) {
    int idx = blockIdx.x * blockDim.x + threadIdx.x;
    if (idx >= KK * 16) return;
    int t = idx >> 4;
    int q = idx & 15;
    int node = order[t];
    float v = (float)sin((double)(t + 1));   // exact arg reduction, matches np
    float* p = h + (size_t)node * HH + q * 4;
    float a = p[0] + v, b = p[1] + v, c = p[2] + v, d = p[3] + v;
    p[0] = a; p[1] = b; p[2] = c; p[3] = d;
    __half2 lo = __floats2half2_rn(a, b);
    __half2 hi = __floats2half2_rn(c, d);
    *(uint2*)&hH[(size_t)node * HH + q * 4] = make_uint2(*(unsigned*)&lo, *(unsigned*)&hi);
    if (q == 0) absorbed[node] = 1;
}

// ---------------- bucket pass 1a: per-block LDS histogram over dst>>8 ----------------
__global__ void k_bcnt(const int* __restrict__ dst, int* __restrict__ gbcnt) {
    __shared__ int hist[NBK];
    int tid = threadIdx.x;
    for (int i = tid; i < NBK; i += 256) hist[i] = 0;
    __syncthreads();
    int e0 = blockIdx.x * EPB;
    int e1 = e0 + EPB < NE ? e0 + EPB : NE;
    for (int e = e0 + tid; e < e1; e += 256)
        atomicAdd(&hist[dst[e] >> 8], 1);
    __syncthreads();
    for (int i = tid; i < NBK; i += 256)
        if (hist[i]) atomicAdd(&gbcnt[i], hist[i]);
}

// ---------------- bucket pass 1b: exclusive scan of 391 bucket sizes ----------------
__global__ void k_bscan(const int* __restrict__ gbcnt, int* __restrict__ bbase) {
    __shared__ int s[512];
    int tid = threadIdx.x;
    int v = (tid < NBK) ? gbcnt[tid] : 0;
    s[tid] = v;
    __syncthreads();
#pragma unroll
    for (int off = 1; off < 512; off <<= 1) {
        int t = (tid >= off) ? s[tid - off] : 0;
        __syncthreads();
        s[tid] += t;
        __syncthreads();
    }
    if (tid < NBK) bbase[tid] = s[tid] - v;
    if (tid == NBK - 1) bbase[NBK] = s[tid];
}

// ---------------- bucket pass 1c: block-span reservation + packed scatter ----------------
// entry = (dst&255)<<20 | src<<3 | rel   (src<2^17, rel<2^3)
__global__ void k_bplace(const int* __restrict__ src, const int* __restrict__ dst,
                         const int* __restrict__ et, const int* __restrict__ bbase,
                         int* __restrict__ bcur, unsigned int* __restrict__ ebuf) {
    __shared__ int hist[NBK];
    __shared__ int lbase[NBK];
    __shared__ int lcur[NBK];
    int tid = threadIdx.x;
    for (int i = tid; i < NBK; i += 256) { hist[i] = 0; lcur[i] = 0; }
    __syncthreads();
    int e0 = blockIdx.x * EPB;
    int e1 = e0 + EPB < NE ? e0 + EPB : NE;
    for (int e = e0 + tid; e < e1; e += 256)
        atomicAdd(&hist[dst[e] >> 8], 1);
    __syncthreads();
    for (int i = tid; i < NBK; i += 256)
        if (hist[i]) lbase[i] = bbase[i] + atomicAdd(&bcur[i], hist[i]);
    __syncthreads();
    for (int e = e0 + tid; e < e1; e += 256) {
        int d = dst[e];
        int b = d >> 8;
        int r = atomicAdd(&lcur[b], 1);
        ebuf[lbase[b] + r] = ((unsigned)(d & 255) << 20) | ((unsigned)src[e] << 3) | (unsigned)et[e];
    }
}

// ---------------- bucket pass 2: per-bucket exact sort + norm + rowstart + epair ----------------
__launch_bounds__(256)
__global__ void k_bsort(const unsigned int* __restrict__ ebuf, const int* __restrict__ bbase,
                        int2* __restrict__ epair, int* __restrict__ rowstart) {
    __shared__ unsigned int el[BCAP];
    __shared__ int cnt5[256 * RR];
    __shared__ float norm5[256 * RR];
    __shared__ int dcur[256];
    __shared__ int s[256];
    int tid = threadIdx.x;
    int b = blockIdx.x;
    int base = bbase[b];
    int sz = bbase[b + 1] - base;
    if (sz > BCAP) sz = BCAP;   // statistically impossible; prevents corruption

    for (int i = tid; i < sz; i += 256) el[i] = ebuf[base + i];
    for (int i = tid; i < 256 * RR; i += 256) cnt5[i] = 0;
    __syncthreads();
    for (int i = tid; i < sz; i += 256) {
        unsigned int e = el[i];
        atomicAdd(&cnt5[(e >> 20) * RR + (e & 7)], 1);
    }
    __syncthreads();
    // per-dst degree + block scan (exclusive)
    int deg = 0;
#pragma unroll
    for (int r = 0; r < RR; r++) deg += cnt5[tid * RR + r];
    s[tid] = deg;
    dcur[tid] = 0;
    __syncthreads();
#pragma unroll
    for (int off = 1; off < 256; off <<= 1) {
        int t = (tid >= off) ? s[tid - off] : 0;
        __syncthreads();
        s[tid] += t;
        __syncthreads();
    }
    int rs = s[tid] - deg;      // exclusive scan
    for (int i = tid; i < 256 * RR; i += 256) {
        int c = cnt5[i];
        norm5[i] = 1.0f / (float)(c > 1 ? c : 1);
    }
    __syncthreads();
    // placement into global epair (one CU -> L2-local writes)
    for (int i = tid; i < sz; i += 256) {
        unsigned int e = el[i];
        int d8 = e >> 20;
        int rk = atomicAdd(&dcur[d8], 1);
        int pos = base + (s[d8] - (cnt5[d8 * RR + 0] + cnt5[d8 * RR + 1] + cnt5[d8 * RR + 2]
                                   + cnt5[d8 * RR + 3] + cnt5[d8 * RR + 4])) + rk;
        epair[pos] = make_int2((int)(e & 0xFFFFFu), __float_as_int(norm5[d8 * RR + (e & 7)]));
    }
    // rowstart
    int d = b * 256 + tid;
    if (d < NN) rowstart[d] = base + rs;
    if (b == 0 && tid == 0) rowstart[NN] = NE;
}

// ---------------- basis-mixed gather (fp16 h -> fp16 mix): wave per dst ----------------
__launch_bounds__(256)
__global__ void k_gather_mix(const int* __restrict__ rowstart, const int2* __restrict__ epair,
                             const float* __restrict__ comp, const unsigned short* __restrict__ hH,
                             unsigned short* __restrict__ mixH) {
    __shared__ float2 lut[8];
    if (threadIdx.x < 8) {
        int r = threadIdx.x < RR ? threadIdx.x : 0;
        lut[threadIdx.x] = make_float2(comp[r * NBB + 0], comp[r * NBB + 1]);
    }
    __syncthreads();
    int wid = (blockIdx.x * blockDim.x + threadIdx.x) >> 6;
    if (wid >= NN) return;
    int lane = threadIdx.x & 63;
    int eg = lane >> 4;          // edge group 0..3
    int dq = lane & 15;          // dim quarter: dims [dq*4, dq*4+4)
    int beg = rowstart[wid], end = rowstart[wid + 1];

    float4 m0 = make_float4(0.f, 0.f, 0.f, 0.f);
    float4 m1 = make_float4(0.f, 0.f, 0.f, 0.f);

    for (int j = beg; j < end; j += 8) {
        int jj0 = j + eg;
        int jj1 = j + 4 + eg;
        int2 pa = (jj0 < end) ? epair[jj0] : make_int2(0, 0);
        int2 pb = (jj1 < end) ? epair[jj1] : make_int2(0, 0);
        uint2 ua = *(const uint2*)&hH[(size_t)(pa.x >> 3) * HH + dq * 4];
        uint2 ub = *(const uint2*)&hH[(size_t)(pb.x >> 3) * HH + dq * 4];
        float2 a01 = __half22float2(*(__half2*)&ua.x);
        float2 a23 = __half22float2(*(__half2*)&ua.y);
        float2 b01 = __half22float2(*(__half2*)&ub.x);
        float2 b23 = __half22float2(*(__half2*)&ub.y);
        float2 ca = lut[pa.x & 7];
        float2 cb = lut[pb.x & 7];
        float na = __int_as_float(pa.y);
        float nb = __int_as_float(pb.y);
        float a0 = ca.x * na, a1 = ca.y * na;
        float b0 = cb.x * nb, b1 = cb.y * nb;
        m0.x += a0 * a01.x; m0.y += a0 * a01.y; m0.z += a0 * a23.x; m0.w += a0 * a23.y;
        m1.x += a1 * a01.x; m1.y += a1 * a01.y; m1.z += a1 * a23.x; m1.w += a1 * a23.y;
        m0.x += b0 * b01.x; m0.y += b0 * b01.y; m0.z += b0 * b23.x; m0.w += b0 * b23.y;
        m1.x += b1 * b01.x; m1.y += b1 * b01.y; m1.z += b1 * b23.x; m1.w += b1 * b23.y;
    }

    // fold the 4 edge groups: butterfly over lane bits 4,5
#pragma unroll
    for (int off = 16; off < 64; off <<= 1) {
        m0.x += __shfl_xor(m0.x, off); m0.y += __shfl_xor(m0.y, off);
        m0.z += __shfl_xor(m0.z, off); m0.w += __shfl_xor(m0.w, off);
        m1.x += __shfl_xor(m1.x, off); m1.y += __shfl_xor(m1.y, off);
        m1.z += __shfl_xor(m1.z, off); m1.w += __shfl_xor(m1.w, off);
    }

    if (eg == 0) {
        __half2 lo = __floats2half2_rn(m0.x, m0.y);
        __half2 hi = __floats2half2_rn(m0.z, m0.w);
        *(uint2*)&mixH[(size_t)wid * 128 + dq * 4] = make_uint2(*(unsigned*)&lo, *(unsigned*)&hi);
    } else if (eg == 1) {
        __half2 lo = __floats2half2_rn(m1.x, m1.y);
        __half2 hi = __floats2half2_rn(m1.z, m1.w);
        *(uint2*)&mixH[(size_t)wid * 128 + 64 + dq * 4] = make_uint2(*(unsigned*)&lo, *(unsigned*)&hi);
    }
}

// ---------------- layer GEMM: hn = [mix0|mix1|h] (K=192) x [B0;B1;root] + bias ----------------
// W in LDS (17.4 KB only); A direct from global: 16 same-ty lanes read the same
// address -> HW broadcast + L1. No manual prefetch arrays (R7 lesson: reg blowup).
__launch_bounds__(256)
__global__ void k_gemmL(const unsigned short* __restrict__ mixH, const float* __restrict__ h,
                        const float* __restrict__ bases, const float* __restrict__ root,
                        const float* __restrict__ bias, float* __restrict__ hn,
                        unsigned short* __restrict__ hnH) {
    __shared__ float ws[64][68];   // [k][o], padded
    int tid = threadIdx.x;
    int n0 = blockIdx.x * 64;
    int tx = tid & 15, ty = tid >> 4;
    int nb = n0 + ty * 4;          // this ty-group's 4 nodes
    float acc[4][4] = {};

    // ---- chunks 0,1: A = mixH (fp16), W = bases ----
    for (int chunk = 0; chunk < 2; ++chunk) {
        __syncthreads();
        for (int i = tid; i < 64 * 16; i += 256) {
            int row = i >> 4, q4 = (i & 15) * 4;
            *(float4*)&ws[row][q4] = *(const float4*)&bases[(size_t)(chunk * 64 + row) * HH + q4];
        }
        __syncthreads();
        const unsigned short* A0 = mixH + chunk * 64;
#pragma unroll 4
        for (int kq = 0; kq < 16; ++kq) {
            float a[4][4];
#pragma unroll
            for (int i = 0; i < 4; ++i) {
                int n = nb + i;
                uint2 u = (n < NN) ? *(const uint2*)&A0[(size_t)n * 128 + kq * 4]
                                   : make_uint2(0, 0);
                float2 lo = __half22float2(*(__half2*)&u.x);
                float2 hi = __half22float2(*(__half2*)&u.y);
                a[i][0] = lo.x; a[i][1] = lo.y; a[i][2] = hi.x; a[i][3] = hi.y;
            }
#pragma unroll
            for (int kk = 0; kk < 4; ++kk) {
                float4 b4 = *(const float4*)&ws[kq * 4 + kk][tx * 4];
                float b[4] = {b4.x, b4.y, b4.z, b4.w};
#pragma unroll
                for (int i = 0; i < 4; ++i)
#pragma unroll
                    for (int j = 0; j < 4; ++j) acc[i][j] += a[i][kk] * b[j];
            }
        }
    }

    // ---- chunk 2: A = h (fp32), W = root ----
    __syncthreads();
    for (int i = tid; i < 64 * 16; i += 256) {
        int row = i >> 4, q4 = (i & 15) * 4;
        *(float4*)&ws[row][q4] = *(const float4*)&root[(size_t)row * HH + q4];
    }
    __syncthreads();
#pragma unroll 4
    for (int kq = 0; kq < 16; ++kq) {
        float a[4][4];
#pragma unroll
        for (int i = 0; i < 4; ++i) {
            int n = nb + i;
            float4 v = (n < NN) ? *(const float4*)&h[(size_t)n * HH + kq * 4]
                                : make_float4(0.f, 0.f, 0.f, 0.f);
            a[i][0] = v.x; a[i][1] = v.y; a[i][2] = v.z; a[i][3] = v.w;
        }
#pragma unroll
        for (int kk = 0; kk < 4; ++kk) {
            float4 b4 = *(const float4*)&ws[kq * 4 + kk][tx * 4];
            float b[4] = {b4.x, b4.y, b4.z, b4.w};
#pragma unroll
            for (int i = 0; i < 4; ++i)
#pragma unroll
                for (int j = 0; j < 4; ++j) acc[i][j] += a[i][kk] * b[j];
        }
    }

    float4 bv = *(const float4*)&bias[tx * 4];
#pragma unroll
    for (int i = 0; i < 4; i++) {
        int n = nb + i;
        if (n >= NN) continue;
        float4 o4 = make_float4(acc[i][0] + bv.x, acc[i][1] + bv.y,
                                acc[i][2] + bv.z, acc[i][3] + bv.w);
        *(float4*)&hn[(size_t)n * HH + tx * 4] = o4;
        if (hnH) {
            __half2 lo = __floats2half2_rn(o4.x, o4.y);
            __half2 hi = __floats2half2_rn(o4.z, o4.w);
            *(uint2*)&hnH[(size_t)n * HH + tx * 4] = make_uint2(*(unsigned*)&lo, *(unsigned*)&hi);
        }
    }
}

// ---------------- layer-2: W2 in LDS + GEMV: xW2[n][r], h2 = root part + bias ----------------
__global__ void k_gemm2(const float* __restrict__ h, const float* __restrict__ bases2,
                        const float* __restrict__ comp2, const float* __restrict__ root2,
                        const float* __restrict__ bias2, float* __restrict__ xW2,
                        float* __restrict__ h2) {
    __shared__ float sW2[6 * HH];
    int tid = threadIdx.x;
    for (int i = tid; i < 6 * HH; i += 256) {
        int c = i >> 6, k = i & 63;
        sW2[i] = (c < RR) ? (comp2[c * NBB + 0] * bases2[k] + comp2[c * NBB + 1] * bases2[HH + k])
                          : root2[k];
    }
    __syncthreads();
    int n = blockIdx.x * blockDim.x + tid;
    if (n >= NN) return;
    float hr[64];
#pragma unroll
    for (int q = 0; q < 16; q++) {
        float4 v = *(const float4*)&h[(size_t)n * HH + q * 4];
        hr[q * 4 + 0] = v.x; hr[q * 4 + 1] = v.y; hr[q * 4 + 2] = v.z; hr[q * 4 + 3] = v.w;
    }
#pragma unroll
    for (int c = 0; c < 6; c++) {
        float acc = 0.f;
#pragma unroll
        for (int k = 0; k < 64; k++) acc += hr[k] * sW2[c * HH + k];
        if (c < RR) xW2[n * RR + c] = acc;
        else        h2[n] = acc + bias2[0];
    }
}

// ---------------- layer-2 gather + fused masked exp-sum ----------------
__global__ void k_gather2(const int* __restrict__ rowstart, const int2* __restrict__ epair,
                          const float* __restrict__ xW2, float* __restrict__ h2,
                          const int* __restrict__ absorbed, float* __restrict__ denom) {
    __shared__ float sdata[256];
    int tid = threadIdx.x;
    int n = blockIdx.x * blockDim.x + tid;
    float local = 0.f;
    if (n < NN) {
        int beg = rowstart[n], end = rowstart[n + 1];
        float acc = h2[n];
        for (int j = beg; j < end; ++j) {
            int2 p = epair[j];
            acc += __int_as_float(p.y) * xW2[(p.x >> 3) * RR + (p.x & 7)];
        }
        h2[n] = acc;
        if (!absorbed[n]) local = expf(acc);
    }
    sdata[tid] = local;
    __syncthreads();
    for (int s = 128; s > 0; s >>= 1) {
        if (tid < s) sdata[tid] += sdata[tid + s];
        __syncthreads();
    }
    if (tid == 0) atomicAdd(denom, sdata[0]);
}

// ---------------- final normalize ----------------
__global__ void k_final(const float* __restrict__ h2, const int* __restrict__ absorbed,
                        const float* __restrict__ denom, float* __restrict__ out) {
    int n = blockIdx.x * blockDim.x + threadIdx.x;
    if (n >= NN) return;
    out[n] = absorbed[n] ? 0.f : expf(h2[n]) / denom[0];
}

extern "C" void kernel_launch(void* const* d_in, const int* in_sizes, int n_in,
                              void* d_out, int out_size, void* d_ws, size_t ws_size,
                              hipStream_t stream) {
    const int* x     = (const int*)d_in[0];
    const int* ei    = (const int*)d_in[1];
    const int* et    = (const int*)d_in[2];
    const int* order = (const int*)d_in[3];
    const float* emb = (const float*)d_in[4];
    const float* bases[3] = {(const float*)d_in[5], (const float*)d_in[9],  (const float*)d_in[13]};
    const float* comp[3]  = {(const float*)d_in[6], (const float*)d_in[10], (const float*)d_in[14]};
    const float* root[3]  = {(const float*)d_in[7], (const float*)d_in[11], (const float*)d_in[15]};
    const float* bias[3]  = {(const float*)d_in[8], (const float*)d_in[12], (const float*)d_in[16]};
    const int* srcp = ei;
    const int* dstp = ei + NE;

    char* w = (char*)d_ws;
    size_t off = 0;
    auto alloc = [&](size_t bytes) -> void* {
        void* p = w + off;
        off = (off + bytes + 255) & ~(size_t)255;
        return p;
    };
    float* h        = (float*)alloc((size_t)NN * HH * 4);
    float* hn       = (float*)alloc((size_t)NN * HH * 4);
    unsigned short* hH   = (unsigned short*)alloc((size_t)NN * HH * 2);
    unsigned short* mixH = (unsigned short*)alloc((size_t)NN * 128 * 2);
    float* xW2      = (float*)alloc((size_t)NN * RR * 4);
    float* h2       = (float*)alloc((size_t)NN * 4);
    int*   absorbed = (int*)alloc((size_t)NN * 4);
    int*   rowstart = (int*)alloc((size_t)(NN + 1) * 4);
    int*   gbcnt    = (int*)alloc((size_t)NBK * 4);
    int*   bcur     = (int*)alloc((size_t)NBK * 4);
    int*   bbase    = (int*)alloc((size_t)(NBK + 1) * 4);
    unsigned int* ebuf = (unsigned int*)alloc((size_t)NE * 4);
    int2*  epair    = (int2*)alloc((size_t)NE * 8);
    float* denom    = (float*)alloc(256);

    // init (also zeroes gbcnt/bcur/absorbed/denom)
    k_init_h<<<(NN * 16 + 255) / 256, 256, 0, stream>>>(x, (const float4*)emb, (float4*)h, hH,
                                                        gbcnt, bcur, absorbed, denom);
    k_pe<<<(KK * 16 + 255) / 256, 256, 0, stream>>>(order, h, hH, absorbed);

    // bucketed CSR build
    k_bcnt<<<256, 256, 0, stream>>>(dstp, gbcnt);
    k_bscan<<<1, 512, 0, stream>>>(gbcnt, bbase);
    k_bplace<<<256, 256, 0, stream>>>(srcp, dstp, et, bbase, bcur, ebuf);
    k_bsort<<<NBK, 256, 0, stream>>>(ebuf, bbase, epair, rowstart);

    int gmix = (NN * 64 + 255) / 256;
    int ggemm = (NN + 63) / 64;

    // layer 0: h -> hn (writes fp16 mirror for next gather)
    k_gather_mix<<<gmix, 256, 0, stream>>>(rowstart, epair, comp[0], hH, mixH);
    k_gemmL<<<ggemm, 256, 0, stream>>>(mixH, h, bases[0], root[0], bias[0], hn, hH);

    // layer 1: hn -> h (no fp16 mirror needed)
    k_gather_mix<<<gmix, 256, 0, stream>>>(rowstart, epair, comp[1], hH, mixH);
    k_gemmL<<<ggemm, 256, 0, stream>>>(mixH, hn, bases[1], root[1], bias[1], h, (unsigned short*)nullptr);

    // layer 2: h -> h2 (W2 built in-kernel; gather fused with exp-reduce)
    k_gemm2<<<(NN + 255) / 256, 256, 0, stream>>>(h, bases[2], comp[2], root[2], bias[2], xW2, h2);
    k_gather2<<<(NN + 255) / 256, 256, 0, stream>>>(rowstart, epair, xW2, h2, absorbed, denom);

    k_final<<<(NN + 255) / 256, 256, 0, stream>>>(h2, absorbed, denom, (float*)d_out);
}

// Round 10
// 262.501 us; speedup vs baseline: 1.4238x; 1.4238x over previous
//
#include <hip/hip_runtime.h>
#include <hip/hip_fp16.h>
#include <math.h>

#define NN 100000
#define NE 1600000
#define RR 5
#define HH 64
#define KK 10000
#define NBB 2
#define NBK 391            // dst buckets of 256 nodes: ceil(100000/256)
#define EPB 6250           // edges per block in bucket passes (256 blocks)
#define BCAP 8192          // pass-2 LDS capacity per bucket (mean 4096, std 64)

typedef _Float16 f16x8 __attribute__((ext_vector_type(8)));
typedef float f32x4 __attribute__((ext_vector_type(4)));

// ---------------- h init: h[n] = emb[x[n]] (fp32 + fp16 mirror) + zero scratch ----------------
__global__ void k_init_h(const int* __restrict__ x, const float4* __restrict__ emb4,
                         float4* __restrict__ h4, unsigned short* __restrict__ hH,
                         int* __restrict__ gbcnt, int* __restrict__ bcur,
                         int* __restrict__ absorbed, float* __restrict__ denom) {
    int idx = blockIdx.x * blockDim.x + threadIdx.x;
    if (idx >= NN * 16) return;
    int n = idx >> 4;
    int q = idx & 15;
    float4 v = emb4[x[n] * 16 + q];
    h4[idx] = v;
    __half2 lo = __floats2half2_rn(v.x, v.y);
    __half2 hi = __floats2half2_rn(v.z, v.w);
    *(uint2*)&hH[(size_t)n * HH + q * 4] = make_uint2(*(unsigned*)&lo, *(unsigned*)&hi);
    // fold in scratch zeroing (completes before dependent kernels by stream order)
    if (idx < NBK) { gbcnt[idx] = 0; bcur[idx] = 0; }
    if (idx == NBK) denom[0] = 0.f;
    if (idx < NN) absorbed[idx] = 0;
}

// ---------------- PE add + absorbed mask (node_order entries distinct) ----------------
__global__ void k_pe(const int* __restrict__ order, float* __restrict__ h,
                     unsigned short* __restrict__ hH, int* __restrict__ absorbed) {
    int idx = blockIdx.x * blockDim.x + threadIdx.x;
    if (idx >= KK * 16) return;
    int t = idx >> 4;
    int q = idx & 15;
    int node = order[t];
    float v = (float)sin((double)(t + 1));   // exact arg reduction, matches np
    float* p = h + (size_t)node * HH + q * 4;
    float a = p[0] + v, b = p[1] + v, c = p[2] + v, d = p[3] + v;
    p[0] = a; p[1] = b; p[2] = c; p[3] = d;
    __half2 lo = __floats2half2_rn(a, b);
    __half2 hi = __floats2half2_rn(c, d);
    *(uint2*)&hH[(size_t)node * HH + q * 4] = make_uint2(*(unsigned*)&lo, *(unsigned*)&hi);
    if (q == 0) absorbed[node] = 1;
}

// ---------------- bucket pass 1a: per-block LDS histogram over dst>>8 ----------------
__global__ void k_bcnt(const int* __restrict__ dst, int* __restrict__ gbcnt) {
    __shared__ int hist[NBK];
    int tid = threadIdx.x;
    for (int i = tid; i < NBK; i += 256) hist[i] = 0;
    __syncthreads();
    int e0 = blockIdx.x * EPB;
    int e1 = e0 + EPB < NE ? e0 + EPB : NE;
    for (int e = e0 + tid; e < e1; e += 256)
        atomicAdd(&hist[dst[e] >> 8], 1);
    __syncthreads();
    for (int i = tid; i < NBK; i += 256)
        if (hist[i]) atomicAdd(&gbcnt[i], hist[i]);
}

// ---------------- bucket pass 1b: exclusive scan of 391 bucket sizes ----------------
__global__ void k_bscan(const int* __restrict__ gbcnt, int* __restrict__ bbase) {
    __shared__ int s[512];
    int tid = threadIdx.x;
    int v = (tid < NBK) ? gbcnt[tid] : 0;
    s[tid] = v;
    __syncthreads();
#pragma unroll
    for (int off = 1; off < 512; off <<= 1) {
        int t = (tid >= off) ? s[tid - off] : 0;
        __syncthreads();
        s[tid] += t;
        __syncthreads();
    }
    if (tid < NBK) bbase[tid] = s[tid] - v;
    if (tid == NBK - 1) bbase[NBK] = s[tid];
}

// ---------------- bucket pass 1c: block-span reservation + packed scatter ----------------
// entry = (dst&255)<<20 | src<<3 | rel   (src<2^17, rel<2^3)
__global__ void k_bplace(const int* __restrict__ src, const int* __restrict__ dst,
                         const int* __restrict__ et, const int* __restrict__ bbase,
                         int* __restrict__ bcur, unsigned int* __restrict__ ebuf) {
    __shared__ int hist[NBK];
    __shared__ int lbase[NBK];
    __shared__ int lcur[NBK];
    int tid = threadIdx.x;
    for (int i = tid; i < NBK; i += 256) { hist[i] = 0; lcur[i] = 0; }
    __syncthreads();
    int e0 = blockIdx.x * EPB;
    int e1 = e0 + EPB < NE ? e0 + EPB : NE;
    for (int e = e0 + tid; e < e1; e += 256)
        atomicAdd(&hist[dst[e] >> 8], 1);
    __syncthreads();
    for (int i = tid; i < NBK; i += 256)
        if (hist[i]) lbase[i] = bbase[i] + atomicAdd(&bcur[i], hist[i]);
    __syncthreads();
    for (int e = e0 + tid; e < e1; e += 256) {
        int d = dst[e];
        int b = d >> 8;
        int r = atomicAdd(&lcur[b], 1);
        ebuf[lbase[b] + r] = ((unsigned)(d & 255) << 20) | ((unsigned)src[e] << 3) | (unsigned)et[e];
    }
}

// ---------------- bucket pass 2: per-bucket exact sort + norm + rowstart + epair ----------------
__launch_bounds__(256)
__global__ void k_bsort(const unsigned int* __restrict__ ebuf, const int* __restrict__ bbase,
                        int2* __restrict__ epair, int* __restrict__ rowstart) {
    __shared__ unsigned int el[BCAP];
    __shared__ int cnt5[256 * RR];
    __shared__ float norm5[256 * RR];
    __shared__ int dcur[256];
    __shared__ int s[256];
    int tid = threadIdx.x;
    int b = blockIdx.x;
    int base = bbase[b];
    int sz = bbase[b + 1] - base;
    if (sz > BCAP) sz = BCAP;   // statistically impossible; prevents corruption

    for (int i = tid; i < sz; i += 256) el[i] = ebuf[base + i];
    for (int i = tid; i < 256 * RR; i += 256) cnt5[i] = 0;
    __syncthreads();
    for (int i = tid; i < sz; i += 256) {
        unsigned int e = el[i];
        atomicAdd(&cnt5[(e >> 20) * RR + (e & 7)], 1);
    }
    __syncthreads();
    // per-dst degree + block scan (exclusive)
    int deg = 0;
#pragma unroll
    for (int r = 0; r < RR; r++) deg += cnt5[tid * RR + r];
    s[tid] = deg;
    dcur[tid] = 0;
    __syncthreads();
#pragma unroll
    for (int off = 1; off < 256; off <<= 1) {
        int t = (tid >= off) ? s[tid - off] : 0;
        __syncthreads();
        s[tid] += t;
        __syncthreads();
    }
    int rs = s[tid] - deg;      // exclusive scan
    for (int i = tid; i < 256 * RR; i += 256) {
        int c = cnt5[i];
        norm5[i] = 1.0f / (float)(c > 1 ? c : 1);
    }
    __syncthreads();
    // placement into global epair (one CU -> L2-local writes)
    for (int i = tid; i < sz; i += 256) {
        unsigned int e = el[i];
        int d8 = e >> 20;
        int rk = atomicAdd(&dcur[d8], 1);
        int pos = base + (s[d8] - (cnt5[d8 * RR + 0] + cnt5[d8 * RR + 1] + cnt5[d8 * RR + 2]
                                   + cnt5[d8 * RR + 3] + cnt5[d8 * RR + 4])) + rk;
        epair[pos] = make_int2((int)(e & 0xFFFFFu), __float_as_int(norm5[d8 * RR + (e & 7)]));
    }
    // rowstart
    int d = b * 256 + tid;
    if (d < NN) rowstart[d] = base + rs;
    if (b == 0 && tid == 0) rowstart[NN] = NE;
}

// ---------------- Wt build: fp16 W^T for both layers: Wt[layer][o][k], k in [0,192) ----------------
__global__ void k_makeWt(const float* __restrict__ b0, const float* __restrict__ r0,
                         const float* __restrict__ b1, const float* __restrict__ r1,
                         unsigned short* __restrict__ Wt) {
    int idx = blockIdx.x * 256 + threadIdx.x;
    if (idx >= 2 * 64 * 192) return;
    int layer = idx / (64 * 192);
    int rem = idx - layer * 64 * 192;
    int o = rem / 192, k = rem - o * 192;
    const float* bases = layer ? b1 : b0;
    const float* root  = layer ? r1 : r0;
    float w = (k < 64)  ? bases[(size_t)k * HH + o]
            : (k < 128) ? bases[(size_t)HH * HH + (size_t)(k - 64) * HH + o]
                        : root[(size_t)(k - 128) * HH + o];
    __half hv = __float2half_rn(w);
    Wt[idx] = *(unsigned short*)&hv;
}

// ---------------- basis-mixed gather (fp16 h -> fp16 mix): wave per dst ----------------
__launch_bounds__(256)
__global__ void k_gather_mix(const int* __restrict__ rowstart, const int2* __restrict__ epair,
                             const float* __restrict__ comp, const unsigned short* __restrict__ hH,
                             unsigned short* __restrict__ mixH) {
    __shared__ float2 lut[8];
    if (threadIdx.x < 8) {
        int r = threadIdx.x < RR ? threadIdx.x : 0;
        lut[threadIdx.x] = make_float2(comp[r * NBB + 0], comp[r * NBB + 1]);
    }
    __syncthreads();
    int wid = (blockIdx.x * blockDim.x + threadIdx.x) >> 6;
    if (wid >= NN) return;
    int lane = threadIdx.x & 63;
    int eg = lane >> 4;          // edge group 0..3
    int dq = lane & 15;          // dim quarter: dims [dq*4, dq*4+4)
    int beg = rowstart[wid], end = rowstart[wid + 1];

    float4 m0 = make_float4(0.f, 0.f, 0.f, 0.f);
    float4 m1 = make_float4(0.f, 0.f, 0.f, 0.f);

    for (int j = beg; j < end; j += 8) {
        int jj0 = j + eg;
        int jj1 = j + 4 + eg;
        int2 pa = (jj0 < end) ? epair[jj0] : make_int2(0, 0);
        int2 pb = (jj1 < end) ? epair[jj1] : make_int2(0, 0);
        uint2 ua = *(const uint2*)&hH[(size_t)(pa.x >> 3) * HH + dq * 4];
        uint2 ub = *(const uint2*)&hH[(size_t)(pb.x >> 3) * HH + dq * 4];
        float2 a01 = __half22float2(*(__half2*)&ua.x);
        float2 a23 = __half22float2(*(__half2*)&ua.y);
        float2 b01 = __half22float2(*(__half2*)&ub.x);
        float2 b23 = __half22float2(*(__half2*)&ub.y);
        float2 ca = lut[pa.x & 7];
        float2 cb = lut[pb.x & 7];
        float na = __int_as_float(pa.y);
        float nb = __int_as_float(pb.y);
        float a0 = ca.x * na, a1 = ca.y * na;
        float b0 = cb.x * nb, b1 = cb.y * nb;
        m0.x += a0 * a01.x; m0.y += a0 * a01.y; m0.z += a0 * a23.x; m0.w += a0 * a23.y;
        m1.x += a1 * a01.x; m1.y += a1 * a01.y; m1.z += a1 * a23.x; m1.w += a1 * a23.y;
        m0.x += b0 * b01.x; m0.y += b0 * b01.y; m0.z += b0 * b23.x; m0.w += b0 * b23.y;
        m1.x += b1 * b01.x; m1.y += b1 * b01.y; m1.z += b1 * b23.x; m1.w += b1 * b23.y;
    }

    // fold the 4 edge groups: butterfly over lane bits 4,5
#pragma unroll
    for (int off = 16; off < 64; off <<= 1) {
        m0.x += __shfl_xor(m0.x, off); m0.y += __shfl_xor(m0.y, off);
        m0.z += __shfl_xor(m0.z, off); m0.w += __shfl_xor(m0.w, off);
        m1.x += __shfl_xor(m1.x, off); m1.y += __shfl_xor(m1.y, off);
        m1.z += __shfl_xor(m1.z, off); m1.w += __shfl_xor(m1.w, off);
    }

    if (eg == 0) {
        __half2 lo = __floats2half2_rn(m0.x, m0.y);
        __half2 hi = __floats2half2_rn(m0.z, m0.w);
        *(uint2*)&mixH[(size_t)wid * 128 + dq * 4] = make_uint2(*(unsigned*)&lo, *(unsigned*)&hi);
    } else if (eg == 1) {
        __half2 lo = __floats2half2_rn(m1.x, m1.y);
        __half2 hi = __floats2half2_rn(m1.z, m1.w);
        *(uint2*)&mixH[(size_t)wid * 128 + 64 + dq * 4] = make_uint2(*(unsigned*)&lo, *(unsigned*)&hi);
    }
}

// ---------------- layer GEMM via MFMA: hn = [mix|hin] (K=192, fp16) x Wt^T + bias ----------------
// Block = 4 waves = 64 nodes. Wave: 16 nodes x 64 outs = 4 tiles of 16x16, 6 K-steps of 32.
// A-frag: lane l holds A[n0+(l&15)][ks*32 + (l>>4)*8 + r]; B-frag: Wt[o=t*16+(l&15)][same k].
// D (m89-verified): col = l&15 (=o), row = (l>>4)*4 + j (=node).
__launch_bounds__(256)
__global__ void k_gemmL(const unsigned short* __restrict__ mixH,
                        const unsigned short* __restrict__ hInH,
                        const unsigned short* __restrict__ Wt,
                        const float* __restrict__ bias, float* __restrict__ hn,
                        unsigned short* __restrict__ hnH) {
    int tid = threadIdx.x;
    int wave = tid >> 6;
    int lane = tid & 63;
    int n0 = blockIdx.x * 64 + wave * 16;
    int lm = lane & 15;
    int lk = (lane >> 4) * 8;
    int nodeA = n0 + lm;
    if (nodeA > NN - 1) nodeA = NN - 1;     // clamp loads; stores guarded below

    f32x4 acc0 = {}, acc1 = {}, acc2 = {}, acc3 = {};

#pragma unroll
    for (int ks = 0; ks < 6; ++ks) {
        f16x8 a;
        if (ks < 4) a = *(const f16x8*)&mixH[(size_t)nodeA * 128 + ks * 32 + lk];
        else        a = *(const f16x8*)&hInH[(size_t)nodeA * HH + (ks - 4) * 32 + lk];
        f16x8 b0 = *(const f16x8*)&Wt[(size_t)(0 * 16 + lm) * 192 + ks * 32 + lk];
        f16x8 b1 = *(const f16x8*)&Wt[(size_t)(1 * 16 + lm) * 192 + ks * 32 + lk];
        f16x8 b2 = *(const f16x8*)&Wt[(size_t)(2 * 16 + lm) * 192 + ks * 32 + lk];
        f16x8 b3 = *(const f16x8*)&Wt[(size_t)(3 * 16 + lm) * 192 + ks * 32 + lk];
        acc0 = __builtin_amdgcn_mfma_f32_16x16x32_f16(a, b0, acc0, 0, 0, 0);
        acc1 = __builtin_amdgcn_mfma_f32_16x16x32_f16(a, b1, acc1, 0, 0, 0);
        acc2 = __builtin_amdgcn_mfma_f32_16x16x32_f16(a, b2, acc2, 0, 0, 0);
        acc3 = __builtin_amdgcn_mfma_f32_16x16x32_f16(a, b3, acc3, 0, 0, 0);
    }

    float bv0 = bias[0 * 16 + lm];
    float bv1 = bias[1 * 16 + lm];
    float bv2 = bias[2 * 16 + lm];
    float bv3 = bias[3 * 16 + lm];

    int nrow = n0 + (lane >> 4) * 4;
#pragma unroll
    for (int j = 0; j < 4; ++j) {
        int node = nrow + j;
        if (node >= NN) continue;
        float v0 = acc0[j] + bv0;
        float v1 = acc1[j] + bv1;
        float v2 = acc2[j] + bv2;
        float v3 = acc3[j] + bv3;
        hn[(size_t)node * HH +  0 + lm] = v0;
        hn[(size_t)node * HH + 16 + lm] = v1;
        hn[(size_t)node * HH + 32 + lm] = v2;
        hn[(size_t)node * HH + 48 + lm] = v3;
        if (hnH) {
            __half h0 = __float2half_rn(v0), h1 = __float2half_rn(v1);
            __half h2 = __float2half_rn(v2), h3 = __float2half_rn(v3);
            hnH[(size_t)node * HH +  0 + lm] = *(unsigned short*)&h0;
            hnH[(size_t)node * HH + 16 + lm] = *(unsigned short*)&h1;
            hnH[(size_t)node * HH + 32 + lm] = *(unsigned short*)&h2;
            hnH[(size_t)node * HH + 48 + lm] = *(unsigned short*)&h3;
        }
    }
}

// ---------------- layer-2: W2 in LDS + GEMV: xW2[n][r], h2 = root part + bias ----------------
__global__ void k_gemm2(const float* __restrict__ h, const float* __restrict__ bases2,
                        const float* __restrict__ comp2, const float* __restrict__ root2,
                        const float* __restrict__ bias2, float* __restrict__ xW2,
                        float* __restrict__ h2) {
    __shared__ float sW2[6 * HH];
    int tid = threadIdx.x;
    for (int i = tid; i < 6 * HH; i += 256) {
        int c = i >> 6, k = i & 63;
        sW2[i] = (c < RR) ? (comp2[c * NBB + 0] * bases2[k] + comp2[c * NBB + 1] * bases2[HH + k])
                          : root2[k];
    }
    __syncthreads();
    int n = blockIdx.x * blockDim.x + tid;
    if (n >= NN) return;
    float hr[64];
#pragma unroll
    for (int q = 0; q < 16; q++) {
        float4 v = *(const float4*)&h[(size_t)n * HH + q * 4];
        hr[q * 4 + 0] = v.x; hr[q * 4 + 1] = v.y; hr[q * 4 + 2] = v.z; hr[q * 4 + 3] = v.w;
    }
#pragma unroll
    for (int c = 0; c < 6; c++) {
        float acc = 0.f;
#pragma unroll
        for (int k = 0; k < 64; k++) acc += hr[k] * sW2[c * HH + k];
        if (c < RR) xW2[n * RR + c] = acc;
        else        h2[n] = acc + bias2[0];
    }
}

// ---------------- layer-2 gather + fused masked exp-sum ----------------
__global__ void k_gather2(const int* __restrict__ rowstart, const int2* __restrict__ epair,
                          const float* __restrict__ xW2, float* __restrict__ h2,
                          const int* __restrict__ absorbed, float* __restrict__ denom) {
    __shared__ float sdata[256];
    int tid = threadIdx.x;
    int n = blockIdx.x * blockDim.x + tid;
    float local = 0.f;
    if (n < NN) {
        int beg = rowstart[n], end = rowstart[n + 1];
        float acc = h2[n];
        for (int j = beg; j < end; ++j) {
            int2 p = epair[j];
            acc += __int_as_float(p.y) * xW2[(p.x >> 3) * RR + (p.x & 7)];
        }
        h2[n] = acc;
        if (!absorbed[n]) local = expf(acc);
    }
    sdata[tid] = local;
    __syncthreads();
    for (int s = 128; s > 0; s >>= 1) {
        if (tid < s) sdata[tid] += sdata[tid + s];
        __syncthreads();
    }
    if (tid == 0) atomicAdd(denom, sdata[0]);
}

// ---------------- final normalize ----------------
__global__ void k_final(const float* __restrict__ h2, const int* __restrict__ absorbed,
                        const float* __restrict__ denom, float* __restrict__ out) {
    int n = blockIdx.x * blockDim.x + threadIdx.x;
    if (n >= NN) return;
    out[n] = absorbed[n] ? 0.f : expf(h2[n]) / denom[0];
}

extern "C" void kernel_launch(void* const* d_in, const int* in_sizes, int n_in,
                              void* d_out, int out_size, void* d_ws, size_t ws_size,
                              hipStream_t stream) {
    const int* x     = (const int*)d_in[0];
    const int* ei    = (const int*)d_in[1];
    const int* et    = (const int*)d_in[2];
    const int* order = (const int*)d_in[3];
    const float* emb = (const float*)d_in[4];
    const float* bases[3] = {(const float*)d_in[5], (const float*)d_in[9],  (const float*)d_in[13]};
    const float* comp[3]  = {(const float*)d_in[6], (const float*)d_in[10], (const float*)d_in[14]};
    const float* root[3]  = {(const float*)d_in[7], (const float*)d_in[11], (const float*)d_in[15]};
    const float* bias[3]  = {(const float*)d_in[8], (const float*)d_in[12], (const float*)d_in[16]};
    const int* srcp = ei;
    const int* dstp = ei + NE;

    char* w = (char*)d_ws;
    size_t off = 0;
    auto alloc = [&](size_t bytes) -> void* {
        void* p = w + off;
        off = (off + bytes + 255) & ~(size_t)255;
        return p;
    };
    float* h        = (float*)alloc((size_t)NN * HH * 4);
    float* hn       = (float*)alloc((size_t)NN * HH * 4);
    unsigned short* hH   = (unsigned short*)alloc((size_t)NN * HH * 2);
    unsigned short* mixH = (unsigned short*)alloc((size_t)NN * 128 * 2);
    float* xW2      = (float*)alloc((size_t)NN * RR * 4);
    float* h2       = (float*)alloc((size_t)NN * 4);
    int*   absorbed = (int*)alloc((size_t)NN * 4);
    int*   rowstart = (int*)alloc((size_t)(NN + 1) * 4);
    int*   gbcnt    = (int*)alloc((size_t)NBK * 4);
    int*   bcur     = (int*)alloc((size_t)NBK * 4);
    int*   bbase    = (int*)alloc((size_t)(NBK + 1) * 4);
    unsigned int* ebuf = (unsigned int*)alloc((size_t)NE * 4);
    int2*  epair    = (int2*)alloc((size_t)NE * 8);
    unsigned short* Wt = (unsigned short*)alloc((size_t)2 * 64 * 192 * 2);
    float* denom    = (float*)alloc(256);

    // init (also zeroes gbcnt/bcur/absorbed/denom)
    k_init_h<<<(NN * 16 + 255) / 256, 256, 0, stream>>>(x, (const float4*)emb, (float4*)h, hH,
                                                        gbcnt, bcur, absorbed, denom);
    k_pe<<<(KK * 16 + 255) / 256, 256, 0, stream>>>(order, h, hH, absorbed);

    // bucketed CSR build + weight transpose
    k_bcnt<<<256, 256, 0, stream>>>(dstp, gbcnt);
    k_makeWt<<<96, 256, 0, stream>>>(bases[0], root[0], bases[1], root[1], Wt);
    k_bscan<<<1, 512, 0, stream>>>(gbcnt, bbase);
    k_bplace<<<256, 256, 0, stream>>>(srcp, dstp, et, bbase, bcur, ebuf);
    k_bsort<<<NBK, 256, 0, stream>>>(ebuf, bbase, epair, rowstart);

    int gmix = (NN * 64 + 255) / 256;
    int ggemm = (NN + 63) / 64;

    // layer 0: h -> hn (writes fp16 mirror of hn into hH for layer 1)
    k_gather_mix<<<gmix, 256, 0, stream>>>(rowstart, epair, comp[0], hH, mixH);
    k_gemmL<<<ggemm, 256, 0, stream>>>(mixH, hH, Wt, bias[0], hn, hH);

    // layer 1: hn -> h (fp32 out for layer 2; no mirror needed)
    k_gather_mix<<<gmix, 256, 0, stream>>>(rowstart, epair, comp[1], hH, mixH);
    k_gemmL<<<ggemm, 256, 0, stream>>>(mixH, hH, Wt + (size_t)64 * 192, bias[1], h,
                                       (unsigned short*)nullptr);

    // layer 2: h -> h2 (W2 built in-kernel; gather fused with exp-reduce)
    k_gemm2<<<(NN + 255) / 256, 256, 0, stream>>>(h, bases[2], comp[2], root[2], bias[2], xW2, h2);
    k_gather2<<<(NN + 255) / 256, 256, 0, stream>>>(rowstart, epair, xW2, h2, absorbed, denom);

    k_final<<<(NN + 255) / 256, 256, 0, stream>>>(h2, absorbed, denom, (float*)d_out);
}

// Round 11
// 234.027 us; speedup vs baseline: 1.5970x; 1.1217x over previous
//
#include <hip/hip_runtime.h>
#include <hip/hip_fp16.h>
#include <math.h>

#define NN 100000
#define NE 1600000
#define RR 5
#define HH 64
#define KK 10000
#define NBB 2
#define NBK 391            // dst buckets of 256 nodes: ceil(100000/256)
#define EPB 6250           // edges per block in bucket passes (256 blocks)
#define BCAP 8192          // pass-2 LDS capacity per bucket (mean 4096, std 64)
#define MPITCH 136         // LDS mix row pitch in halves (128 + 8 pad)

typedef _Float16 f16x8 __attribute__((ext_vector_type(8)));
typedef float f32x4 __attribute__((ext_vector_type(4)));

// ---------------- h init: hH[n] = fp16(emb[x[n]]) + zero scratch ----------------
__global__ void k_init_h(const int* __restrict__ x, const float4* __restrict__ emb4,
                         unsigned short* __restrict__ hH,
                         int* __restrict__ gbcnt, int* __restrict__ bcur,
                         int* __restrict__ absorbed, float* __restrict__ denom) {
    int idx = blockIdx.x * blockDim.x + threadIdx.x;
    if (idx >= NN * 16) return;
    int n = idx >> 4;
    int q = idx & 15;
    float4 v = emb4[x[n] * 16 + q];
    __half2 lo = __floats2half2_rn(v.x, v.y);
    __half2 hi = __floats2half2_rn(v.z, v.w);
    *(uint2*)&hH[(size_t)n * HH + q * 4] = make_uint2(*(unsigned*)&lo, *(unsigned*)&hi);
    if (idx < NBK) { gbcnt[idx] = 0; bcur[idx] = 0; }
    if (idx == NBK) denom[0] = 0.f;
    if (idx < NN) absorbed[idx] = 0;
}

// ---------------- PE add + absorbed mask (fp16 in-place; node_order entries distinct) ----------------
__global__ void k_pe(const int* __restrict__ order, unsigned short* __restrict__ hH,
                     int* __restrict__ absorbed) {
    int idx = blockIdx.x * blockDim.x + threadIdx.x;
    if (idx >= KK * 16) return;
    int t = idx >> 4;
    int q = idx & 15;
    int node = order[t];
    float v = (float)sin((double)(t + 1));   // exact arg reduction, matches np
    uint2 u = *(uint2*)&hH[(size_t)node * HH + q * 4];
    float2 lo = __half22float2(*(__half2*)&u.x);
    float2 hi = __half22float2(*(__half2*)&u.y);
    __half2 nlo = __floats2half2_rn(lo.x + v, lo.y + v);
    __half2 nhi = __floats2half2_rn(hi.x + v, hi.y + v);
    *(uint2*)&hH[(size_t)node * HH + q * 4] = make_uint2(*(unsigned*)&nlo, *(unsigned*)&nhi);
    if (q == 0) absorbed[node] = 1;
}

// ---------------- bucket pass 1a: per-block LDS histogram over dst>>8 ----------------
__global__ void k_bcnt(const int* __restrict__ dst, int* __restrict__ gbcnt) {
    __shared__ int hist[NBK];
    int tid = threadIdx.x;
    for (int i = tid; i < NBK; i += 256) hist[i] = 0;
    __syncthreads();
    int e0 = blockIdx.x * EPB;
    int e1 = e0 + EPB < NE ? e0 + EPB : NE;
    for (int e = e0 + tid; e < e1; e += 256)
        atomicAdd(&hist[dst[e] >> 8], 1);
    __syncthreads();
    for (int i = tid; i < NBK; i += 256)
        if (hist[i]) atomicAdd(&gbcnt[i], hist[i]);
}

// ---------------- bucket pass 1b: exclusive scan of 391 bucket sizes ----------------
__global__ void k_bscan(const int* __restrict__ gbcnt, int* __restrict__ bbase) {
    __shared__ int s[512];
    int tid = threadIdx.x;
    int v = (tid < NBK) ? gbcnt[tid] : 0;
    s[tid] = v;
    __syncthreads();
#pragma unroll
    for (int off = 1; off < 512; off <<= 1) {
        int t = (tid >= off) ? s[tid - off] : 0;
        __syncthreads();
        s[tid] += t;
        __syncthreads();
    }
    if (tid < NBK) bbase[tid] = s[tid] - v;
    if (tid == NBK - 1) bbase[NBK] = s[tid];
}

// ---------------- bucket pass 1c: block-span reservation + packed scatter ----------------
// entry = (dst&255)<<20 | src<<3 | rel   (src<2^17, rel<2^3)
__global__ void k_bplace(const int* __restrict__ src, const int* __restrict__ dst,
                         const int* __restrict__ et, const int* __restrict__ bbase,
                         int* __restrict__ bcur, unsigned int* __restrict__ ebuf) {
    __shared__ int hist[NBK];
    __shared__ int lbase[NBK];
    __shared__ int lcur[NBK];
    int tid = threadIdx.x;
    for (int i = tid; i < NBK; i += 256) { hist[i] = 0; lcur[i] = 0; }
    __syncthreads();
    int e0 = blockIdx.x * EPB;
    int e1 = e0 + EPB < NE ? e0 + EPB : NE;
    for (int e = e0 + tid; e < e1; e += 256)
        atomicAdd(&hist[dst[e] >> 8], 1);
    __syncthreads();
    for (int i = tid; i < NBK; i += 256)
        if (hist[i]) lbase[i] = bbase[i] + atomicAdd(&bcur[i], hist[i]);
    __syncthreads();
    for (int e = e0 + tid; e < e1; e += 256) {
        int d = dst[e];
        int b = d >> 8;
        int r = atomicAdd(&lcur[b], 1);
        ebuf[lbase[b] + r] = ((unsigned)(d & 255) << 20) | ((unsigned)src[e] << 3) | (unsigned)et[e];
    }
}

// ---------------- bucket pass 2: per-bucket exact sort + norm + rowstart + epair ----------------
__launch_bounds__(256)
__global__ void k_bsort(const unsigned int* __restrict__ ebuf, const int* __restrict__ bbase,
                        int2* __restrict__ epair, int* __restrict__ rowstart) {
    __shared__ unsigned int el[BCAP];
    __shared__ int cnt5[256 * RR];
    __shared__ float norm5[256 * RR];
    __shared__ int dcur[256];
    __shared__ int s[256];
    int tid = threadIdx.x;
    int b = blockIdx.x;
    int base = bbase[b];
    int sz = bbase[b + 1] - base;
    if (sz > BCAP) sz = BCAP;   // statistically impossible; prevents corruption

    for (int i = tid; i < sz; i += 256) el[i] = ebuf[base + i];
    for (int i = tid; i < 256 * RR; i += 256) cnt5[i] = 0;
    __syncthreads();
    for (int i = tid; i < sz; i += 256) {
        unsigned int e = el[i];
        atomicAdd(&cnt5[(e >> 20) * RR + (e & 7)], 1);
    }
    __syncthreads();
    // per-dst degree + block scan (exclusive)
    int deg = 0;
#pragma unroll
    for (int r = 0; r < RR; r++) deg += cnt5[tid * RR + r];
    s[tid] = deg;
    dcur[tid] = 0;
    __syncthreads();
#pragma unroll
    for (int off = 1; off < 256; off <<= 1) {
        int t = (tid >= off) ? s[tid - off] : 0;
        __syncthreads();
        s[tid] += t;
        __syncthreads();
    }
    int rs = s[tid] - deg;      // exclusive scan
    for (int i = tid; i < 256 * RR; i += 256) {
        int c = cnt5[i];
        norm5[i] = 1.0f / (float)(c > 1 ? c : 1);
    }
    __syncthreads();
    // placement into global epair (one CU -> L2-local writes)
    for (int i = tid; i < sz; i += 256) {
        unsigned int e = el[i];
        int d8 = e >> 20;
        int rk = atomicAdd(&dcur[d8], 1);
        int pos = base + (s[d8] - (cnt5[d8 * RR + 0] + cnt5[d8 * RR + 1] + cnt5[d8 * RR + 2]
                                   + cnt5[d8 * RR + 3] + cnt5[d8 * RR + 4])) + rk;
        epair[pos] = make_int2((int)(e & 0xFFFFFu), __float_as_int(norm5[d8 * RR + (e & 7)]));
    }
    // rowstart
    int d = b * 256 + tid;
    if (d < NN) rowstart[d] = base + rs;
    if (b == 0 && tid == 0) rowstart[NN] = NE;
}

// ---------------- Wt build: fp16 W^T for both layers: Wt[layer][o][k], k in [0,192) ----------------
__global__ void k_makeWt(const float* __restrict__ b0, const float* __restrict__ r0,
                         const float* __restrict__ b1, const float* __restrict__ r1,
                         unsigned short* __restrict__ Wt) {
    int idx = blockIdx.x * 256 + threadIdx.x;
    if (idx >= 2 * 64 * 192) return;
    int layer = idx / (64 * 192);
    int rem = idx - layer * 64 * 192;
    int o = rem / 192, k = rem - o * 192;
    const float* bases = layer ? b1 : b0;
    const float* root  = layer ? r1 : r0;
    float w = (k < 64)  ? bases[(size_t)k * HH + o]
            : (k < 128) ? bases[(size_t)HH * HH + (size_t)(k - 64) * HH + o]
                        : root[(size_t)(k - 128) * HH + o];
    __half hv = __float2half_rn(w);
    Wt[idx] = *(unsigned short*)&hv;
}

// ---------------- fused layer: gather-mix into LDS, then MFMA GEMM ----------------
// Block = 64 dst nodes, 4 waves. Phase 1: wave w gathers nodes [n0+16w, n0+16w+16),
// folds 4 edge-groups, stores fp16 mix rows to LDS. Phase 2: MFMA (16x16x32_f16),
// K=192 = [mix(128, LDS) | h_in(64, global fp16)], out = fp16 only.
__launch_bounds__(256)
__global__ void k_layer(const int* __restrict__ rowstart, const int2* __restrict__ epair,
                        const float* __restrict__ comp, const unsigned short* __restrict__ hH,
                        const unsigned short* __restrict__ Wt, const float* __restrict__ bias,
                        unsigned short* __restrict__ outH) {
    __shared__ float2 lut[8];
    __shared__ _Float16 mixs[64][MPITCH];
    int tid = threadIdx.x;
    int wave = tid >> 6;
    int lane = tid & 63;
    if (tid < 8) {
        int r = tid < RR ? tid : 0;
        lut[tid] = make_float2(comp[r * NBB + 0], comp[r * NBB + 1]);
    }
    __syncthreads();

    int n0 = blockIdx.x * 64;
    int eg = lane >> 4;          // edge group 0..3
    int dq = lane & 15;          // dim quarter

    // ---- phase 1: gather 16 nodes per wave ----
    for (int i = 0; i < 16; ++i) {
        int node = n0 + wave * 16 + i;
        float4 m0 = make_float4(0.f, 0.f, 0.f, 0.f);
        float4 m1 = make_float4(0.f, 0.f, 0.f, 0.f);
        if (node < NN) {
            int beg = rowstart[node], end = rowstart[node + 1];
            for (int j = beg; j < end; j += 8) {
                int jj0 = j + eg;
                int jj1 = j + 4 + eg;
                int2 pa = (jj0 < end) ? epair[jj0] : make_int2(0, 0);
                int2 pb = (jj1 < end) ? epair[jj1] : make_int2(0, 0);
                uint2 ua = *(const uint2*)&hH[(size_t)(pa.x >> 3) * HH + dq * 4];
                uint2 ub = *(const uint2*)&hH[(size_t)(pb.x >> 3) * HH + dq * 4];
                float2 a01 = __half22float2(*(__half2*)&ua.x);
                float2 a23 = __half22float2(*(__half2*)&ua.y);
                float2 b01 = __half22float2(*(__half2*)&ub.x);
                float2 b23 = __half22float2(*(__half2*)&ub.y);
                float2 ca = lut[pa.x & 7];
                float2 cb = lut[pb.x & 7];
                float na = __int_as_float(pa.y);
                float nb = __int_as_float(pb.y);
                float a0 = ca.x * na, a1 = ca.y * na;
                float b0 = cb.x * nb, b1 = cb.y * nb;
                m0.x += a0 * a01.x; m0.y += a0 * a01.y; m0.z += a0 * a23.x; m0.w += a0 * a23.y;
                m1.x += a1 * a01.x; m1.y += a1 * a01.y; m1.z += a1 * a23.x; m1.w += a1 * a23.y;
                m0.x += b0 * b01.x; m0.y += b0 * b01.y; m0.z += b0 * b23.x; m0.w += b0 * b23.y;
                m1.x += b1 * b01.x; m1.y += b1 * b01.y; m1.z += b1 * b23.x; m1.w += b1 * b23.y;
            }
        }
#pragma unroll
        for (int off = 16; off < 64; off <<= 1) {
            m0.x += __shfl_xor(m0.x, off); m0.y += __shfl_xor(m0.y, off);
            m0.z += __shfl_xor(m0.z, off); m0.w += __shfl_xor(m0.w, off);
            m1.x += __shfl_xor(m1.x, off); m1.y += __shfl_xor(m1.y, off);
            m1.z += __shfl_xor(m1.z, off); m1.w += __shfl_xor(m1.w, off);
        }
        int row = wave * 16 + i;
        if (eg == 0) {
            __half2 lo = __floats2half2_rn(m0.x, m0.y);
            __half2 hi = __floats2half2_rn(m0.z, m0.w);
            *(uint2*)&mixs[row][dq * 4] = make_uint2(*(unsigned*)&lo, *(unsigned*)&hi);
        } else if (eg == 1) {
            __half2 lo = __floats2half2_rn(m1.x, m1.y);
            __half2 hi = __floats2half2_rn(m1.z, m1.w);
            *(uint2*)&mixs[row][64 + dq * 4] = make_uint2(*(unsigned*)&lo, *(unsigned*)&hi);
        }
    }
    __syncthreads();

    // ---- phase 2: MFMA ----
    int lm = lane & 15;
    int lk = (lane >> 4) * 8;
    int rowA = wave * 16 + lm;
    int nodeA = n0 + rowA;
    int nodeClamp = nodeA < NN ? nodeA : NN - 1;

    f32x4 acc0 = {}, acc1 = {}, acc2 = {}, acc3 = {};
#pragma unroll
    for (int ks = 0; ks < 6; ++ks) {
        f16x8 a;
        if (ks < 4) a = *(const f16x8*)&mixs[rowA][ks * 32 + lk];
        else        a = *(const f16x8*)&hH[(size_t)nodeClamp * HH + (ks - 4) * 32 + lk];
        f16x8 b0 = *(const f16x8*)&Wt[(size_t)(0 * 16 + lm) * 192 + ks * 32 + lk];
        f16x8 b1 = *(const f16x8*)&Wt[(size_t)(1 * 16 + lm) * 192 + ks * 32 + lk];
        f16x8 b2 = *(const f16x8*)&Wt[(size_t)(2 * 16 + lm) * 192 + ks * 32 + lk];
        f16x8 b3 = *(const f16x8*)&Wt[(size_t)(3 * 16 + lm) * 192 + ks * 32 + lk];
        acc0 = __builtin_amdgcn_mfma_f32_16x16x32_f16(a, b0, acc0, 0, 0, 0);
        acc1 = __builtin_amdgcn_mfma_f32_16x16x32_f16(a, b1, acc1, 0, 0, 0);
        acc2 = __builtin_amdgcn_mfma_f32_16x16x32_f16(a, b2, acc2, 0, 0, 0);
        acc3 = __builtin_amdgcn_mfma_f32_16x16x32_f16(a, b3, acc3, 0, 0, 0);
    }

    float bv0 = bias[0 * 16 + lm];
    float bv1 = bias[1 * 16 + lm];
    float bv2 = bias[2 * 16 + lm];
    float bv3 = bias[3 * 16 + lm];

    int nrow = n0 + wave * 16 + (lane >> 4) * 4;
#pragma unroll
    for (int j = 0; j < 4; ++j) {
        int node = nrow + j;
        if (node >= NN) continue;
        __half h0 = __float2half_rn(acc0[j] + bv0);
        __half h1 = __float2half_rn(acc1[j] + bv1);
        __half h2 = __float2half_rn(acc2[j] + bv2);
        __half h3 = __float2half_rn(acc3[j] + bv3);
        outH[(size_t)node * HH +  0 + lm] = *(unsigned short*)&h0;
        outH[(size_t)node * HH + 16 + lm] = *(unsigned short*)&h1;
        outH[(size_t)node * HH + 32 + lm] = *(unsigned short*)&h2;
        outH[(size_t)node * HH + 48 + lm] = *(unsigned short*)&h3;
    }
}

// ---------------- layer-2: W2 in LDS + fp16-input GEMV: xW2[n][r], h2 = root part + bias ----------------
__global__ void k_gemm2(const unsigned short* __restrict__ hH, const float* __restrict__ bases2,
                        const float* __restrict__ comp2, const float* __restrict__ root2,
                        const float* __restrict__ bias2, float* __restrict__ xW2,
                        float* __restrict__ h2) {
    __shared__ float sW2[6 * HH];
    int tid = threadIdx.x;
    for (int i = tid; i < 6 * HH; i += 256) {
        int c = i >> 6, k = i & 63;
        sW2[i] = (c < RR) ? (comp2[c * NBB + 0] * bases2[k] + comp2[c * NBB + 1] * bases2[HH + k])
                          : root2[k];
    }
    __syncthreads();
    int n = blockIdx.x * blockDim.x + tid;
    if (n >= NN) return;
    float hr[64];
#pragma unroll
    for (int q = 0; q < 16; q++) {
        uint2 u = *(const uint2*)&hH[(size_t)n * HH + q * 4];
        float2 lo = __half22float2(*(__half2*)&u.x);
        float2 hi = __half22float2(*(__half2*)&u.y);
        hr[q * 4 + 0] = lo.x; hr[q * 4 + 1] = lo.y; hr[q * 4 + 2] = hi.x; hr[q * 4 + 3] = hi.y;
    }
#pragma unroll
    for (int c = 0; c < 6; c++) {
        float acc = 0.f;
#pragma unroll
        for (int k = 0; k < 64; k++) acc += hr[k] * sW2[c * HH + k];
        if (c < RR) xW2[n * RR + c] = acc;
        else        h2[n] = acc + bias2[0];
    }
}

// ---------------- layer-2 gather + fused masked exp-sum ----------------
__global__ void k_gather2(const int* __restrict__ rowstart, const int2* __restrict__ epair,
                          const float* __restrict__ xW2, float* __restrict__ h2,
                          const int* __restrict__ absorbed, float* __restrict__ denom) {
    __shared__ float sdata[256];
    int tid = threadIdx.x;
    int n = blockIdx.x * blockDim.x + tid;
    float local = 0.f;
    if (n < NN) {
        int beg = rowstart[n], end = rowstart[n + 1];
        float acc = h2[n];
        for (int j = beg; j < end; ++j) {
            int2 p = epair[j];
            acc += __int_as_float(p.y) * xW2[(p.x >> 3) * RR + (p.x & 7)];
        }
        h2[n] = acc;
        if (!absorbed[n]) local = expf(acc);
    }
    sdata[tid] = local;
    __syncthreads();
    for (int s = 128; s > 0; s >>= 1) {
        if (tid < s) sdata[tid] += sdata[tid + s];
        __syncthreads();
    }
    if (tid == 0) atomicAdd(denom, sdata[0]);
}

// ---------------- final normalize ----------------
__global__ void k_final(const float* __restrict__ h2, const int* __restrict__ absorbed,
                        const float* __restrict__ denom, float* __restrict__ out) {
    int n = blockIdx.x * blockDim.x + threadIdx.x;
    if (n >= NN) return;
    out[n] = absorbed[n] ? 0.f : expf(h2[n]) / denom[0];
}

extern "C" void kernel_launch(void* const* d_in, const int* in_sizes, int n_in,
                              void* d_out, int out_size, void* d_ws, size_t ws_size,
                              hipStream_t stream) {
    const int* x     = (const int*)d_in[0];
    const int* ei    = (const int*)d_in[1];
    const int* et    = (const int*)d_in[2];
    const int* order = (const int*)d_in[3];
    const float* emb = (const float*)d_in[4];
    const float* bases[3] = {(const float*)d_in[5], (const float*)d_in[9],  (const float*)d_in[13]};
    const float* comp[3]  = {(const float*)d_in[6], (const float*)d_in[10], (const float*)d_in[14]};
    const float* root[3]  = {(const float*)d_in[7], (const float*)d_in[11], (const float*)d_in[15]};
    const float* bias[3]  = {(const float*)d_in[8], (const float*)d_in[12], (const float*)d_in[16]};
    const int* srcp = ei;
    const int* dstp = ei + NE;

    char* w = (char*)d_ws;
    size_t off = 0;
    auto alloc = [&](size_t bytes) -> void* {
        void* p = w + off;
        off = (off + bytes + 255) & ~(size_t)255;
        return p;
    };
    unsigned short* hHa = (unsigned short*)alloc((size_t)NN * HH * 2);
    unsigned short* hHb = (unsigned short*)alloc((size_t)NN * HH * 2);
    float* xW2      = (float*)alloc((size_t)NN * RR * 4);
    float* h2       = (float*)alloc((size_t)NN * 4);
    int*   absorbed = (int*)alloc((size_t)NN * 4);
    int*   rowstart = (int*)alloc((size_t)(NN + 1) * 4);
    int*   gbcnt    = (int*)alloc((size_t)NBK * 4);
    int*   bcur     = (int*)alloc((size_t)NBK * 4);
    int*   bbase    = (int*)alloc((size_t)(NBK + 1) * 4);
    unsigned int* ebuf = (unsigned int*)alloc((size_t)NE * 4);
    int2*  epair    = (int2*)alloc((size_t)NE * 8);
    unsigned short* Wt = (unsigned short*)alloc((size_t)2 * 64 * 192 * 2);
    float* denom    = (float*)alloc(256);

    // init (also zeroes gbcnt/bcur/absorbed/denom)
    k_init_h<<<(NN * 16 + 255) / 256, 256, 0, stream>>>(x, (const float4*)emb, hHa,
                                                        gbcnt, bcur, absorbed, denom);
    k_pe<<<(KK * 16 + 255) / 256, 256, 0, stream>>>(order, hHa, absorbed);

    // bucketed CSR build + weight transpose
    k_bcnt<<<256, 256, 0, stream>>>(dstp, gbcnt);
    k_makeWt<<<96, 256, 0, stream>>>(bases[0], root[0], bases[1], root[1], Wt);
    k_bscan<<<1, 512, 0, stream>>>(gbcnt, bbase);
    k_bplace<<<256, 256, 0, stream>>>(srcp, dstp, et, bbase, bcur, ebuf);
    k_bsort<<<NBK, 256, 0, stream>>>(ebuf, bbase, epair, rowstart);

    int glayer = (NN + 63) / 64;

    // layer 0: hHa -> hHb ; layer 1: hHb -> hHa
    k_layer<<<glayer, 256, 0, stream>>>(rowstart, epair, comp[0], hHa, Wt, bias[0], hHb);
    k_layer<<<glayer, 256, 0, stream>>>(rowstart, epair, comp[1], hHb, Wt + (size_t)64 * 192,
                                        bias[1], hHa);

    // layer 2: hHa -> h2 (W2 built in-kernel; gather fused with exp-reduce)
    k_gemm2<<<(NN + 255) / 256, 256, 0, stream>>>(hHa, bases[2], comp[2], root[2], bias[2], xW2, h2);
    k_gather2<<<(NN + 255) / 256, 256, 0, stream>>>(rowstart, epair, xW2, h2, absorbed, denom);

    k_final<<<(NN + 255) / 256, 256, 0, stream>>>(h2, absorbed, denom, (float*)d_out);
}

// Round 12
// 220.771 us; speedup vs baseline: 1.6929x; 1.0600x over previous
//
#include <hip/hip_runtime.h>
#include <hip/hip_fp16.h>
#include <math.h>

#define NN 100000
#define NE 1600000
#define RR 5
#define HH 64
#define KK 10000
#define NBB 2
#define NBK 391            // dst buckets of 256 nodes: ceil(100000/256)
#define EPB 6250           // edges per block in bucket passes (256 blocks)
#define BCAP 8192          // pass-2 LDS capacity per bucket (mean 4096, std 64)
#define MPITCH 136         // LDS mix row pitch in halves (272 B = 17*16 -> b128-aligned rows)

typedef _Float16 f16x8 __attribute__((ext_vector_type(8)));
typedef float f32x4 __attribute__((ext_vector_type(4)));

// ---------------- h init: hH[n] = fp16(emb[x[n]]) + zero scratch ----------------
__global__ void k_init_h(const int* __restrict__ x, const float4* __restrict__ emb4,
                         unsigned short* __restrict__ hH,
                         int* __restrict__ gbcnt, int* __restrict__ bcur,
                         int* __restrict__ absorbed, float* __restrict__ denom) {
    int idx = blockIdx.x * blockDim.x + threadIdx.x;
    if (idx >= NN * 16) return;
    int n = idx >> 4;
    int q = idx & 15;
    float4 v = emb4[x[n] * 16 + q];
    __half2 lo = __floats2half2_rn(v.x, v.y);
    __half2 hi = __floats2half2_rn(v.z, v.w);
    *(uint2*)&hH[(size_t)n * HH + q * 4] = make_uint2(*(unsigned*)&lo, *(unsigned*)&hi);
    if (idx < NBK) { gbcnt[idx] = 0; bcur[idx] = 0; }
    if (idx == NBK) denom[0] = 0.f;
    if (idx < NN) absorbed[idx] = 0;
}

// ---------------- PE add + absorbed mask (fp16 in-place; node_order entries distinct) ----------------
__global__ void k_pe(const int* __restrict__ order, unsigned short* __restrict__ hH,
                     int* __restrict__ absorbed) {
    int idx = blockIdx.x * blockDim.x + threadIdx.x;
    if (idx >= KK * 16) return;
    int t = idx >> 4;
    int q = idx & 15;
    int node = order[t];
    float v = (float)sin((double)(t + 1));   // exact arg reduction, matches np
    uint2 u = *(uint2*)&hH[(size_t)node * HH + q * 4];
    float2 lo = __half22float2(*(__half2*)&u.x);
    float2 hi = __half22float2(*(__half2*)&u.y);
    __half2 nlo = __floats2half2_rn(lo.x + v, lo.y + v);
    __half2 nhi = __floats2half2_rn(hi.x + v, hi.y + v);
    *(uint2*)&hH[(size_t)node * HH + q * 4] = make_uint2(*(unsigned*)&nlo, *(unsigned*)&nhi);
    if (q == 0) absorbed[node] = 1;
}

// ---------------- bucket pass 1a: per-block LDS histogram over dst>>8 ----------------
__global__ void k_bcnt(const int* __restrict__ dst, int* __restrict__ gbcnt) {
    __shared__ int hist[NBK];
    int tid = threadIdx.x;
    for (int i = tid; i < NBK; i += 256) hist[i] = 0;
    __syncthreads();
    int e0 = blockIdx.x * EPB;
    int e1 = e0 + EPB < NE ? e0 + EPB : NE;
    for (int e = e0 + tid; e < e1; e += 256)
        atomicAdd(&hist[dst[e] >> 8], 1);
    __syncthreads();
    for (int i = tid; i < NBK; i += 256)
        if (hist[i]) atomicAdd(&gbcnt[i], hist[i]);
}

// ---------------- bucket pass 1b: exclusive scan of 391 bucket sizes ----------------
__global__ void k_bscan(const int* __restrict__ gbcnt, int* __restrict__ bbase) {
    __shared__ int s[512];
    int tid = threadIdx.x;
    int v = (tid < NBK) ? gbcnt[tid] : 0;
    s[tid] = v;
    __syncthreads();
#pragma unroll
    for (int off = 1; off < 512; off <<= 1) {
        int t = (tid >= off) ? s[tid - off] : 0;
        __syncthreads();
        s[tid] += t;
        __syncthreads();
    }
    if (tid < NBK) bbase[tid] = s[tid] - v;
    if (tid == NBK - 1) bbase[NBK] = s[tid];
}

// ---------------- bucket pass 1c: block-span reservation + packed scatter ----------------
// entry = (dst&255)<<20 | src<<3 | rel   (src<2^17, rel<2^3)
__global__ void k_bplace(const int* __restrict__ src, const int* __restrict__ dst,
                         const int* __restrict__ et, const int* __restrict__ bbase,
                         int* __restrict__ bcur, unsigned int* __restrict__ ebuf) {
    __shared__ int hist[NBK];
    __shared__ int lbase[NBK];
    __shared__ int lcur[NBK];
    int tid = threadIdx.x;
    for (int i = tid; i < NBK; i += 256) { hist[i] = 0; lcur[i] = 0; }
    __syncthreads();
    int e0 = blockIdx.x * EPB;
    int e1 = e0 + EPB < NE ? e0 + EPB : NE;
    for (int e = e0 + tid; e < e1; e += 256)
        atomicAdd(&hist[dst[e] >> 8], 1);
    __syncthreads();
    for (int i = tid; i < NBK; i += 256)
        if (hist[i]) lbase[i] = bbase[i] + atomicAdd(&bcur[i], hist[i]);
    __syncthreads();
    for (int e = e0 + tid; e < e1; e += 256) {
        int d = dst[e];
        int b = d >> 8;
        int r = atomicAdd(&lcur[b], 1);
        ebuf[lbase[b] + r] = ((unsigned)(d & 255) << 20) | ((unsigned)src[e] << 3) | (unsigned)et[e];
    }
}

// ---------------- bucket pass 2: per-bucket exact sort + norm + rowstart + epair ----------------
__launch_bounds__(256)
__global__ void k_bsort(const unsigned int* __restrict__ ebuf, const int* __restrict__ bbase,
                        int2* __restrict__ epair, int* __restrict__ rowstart) {
    __shared__ unsigned int el[BCAP];
    __shared__ int cnt5[256 * RR];
    __shared__ float norm5[256 * RR];
    __shared__ int dcur[256];
    __shared__ int s[256];
    int tid = threadIdx.x;
    int b = blockIdx.x;
    int base = bbase[b];
    int sz = bbase[b + 1] - base;
    if (sz > BCAP) sz = BCAP;   // statistically impossible; prevents corruption

    for (int i = tid; i < sz; i += 256) el[i] = ebuf[base + i];
    for (int i = tid; i < 256 * RR; i += 256) cnt5[i] = 0;
    __syncthreads();
    for (int i = tid; i < sz; i += 256) {
        unsigned int e = el[i];
        atomicAdd(&cnt5[(e >> 20) * RR + (e & 7)], 1);
    }
    __syncthreads();
    // per-dst degree + block scan (exclusive)
    int deg = 0;
#pragma unroll
    for (int r = 0; r < RR; r++) deg += cnt5[tid * RR + r];
    s[tid] = deg;
    dcur[tid] = 0;
    __syncthreads();
#pragma unroll
    for (int off = 1; off < 256; off <<= 1) {
        int t = (tid >= off) ? s[tid - off] : 0;
        __syncthreads();
        s[tid] += t;
        __syncthreads();
    }
    int rs = s[tid] - deg;      // exclusive scan
    for (int i = tid; i < 256 * RR; i += 256) {
        int c = cnt5[i];
        norm5[i] = 1.0f / (float)(c > 1 ? c : 1);
    }
    __syncthreads();
    // placement into global epair (one CU -> L2-local writes)
    for (int i = tid; i < sz; i += 256) {
        unsigned int e = el[i];
        int d8 = e >> 20;
        int rk = atomicAdd(&dcur[d8], 1);
        int pos = base + (s[d8] - (cnt5[d8 * RR + 0] + cnt5[d8 * RR + 1] + cnt5[d8 * RR + 2]
                                   + cnt5[d8 * RR + 3] + cnt5[d8 * RR + 4])) + rk;
        epair[pos] = make_int2((int)(e & 0xFFFFFu), __float_as_int(norm5[d8 * RR + (e & 7)]));
    }
    // rowstart
    int d = b * 256 + tid;
    if (d < NN) rowstart[d] = base + rs;
    if (b == 0 && tid == 0) rowstart[NN] = NE;
}

// ---------------- Wt build: fp16 W^T for both layers: Wt[layer][o][k], k in [0,192) ----------------
__global__ void k_makeWt(const float* __restrict__ b0, const float* __restrict__ r0,
                         const float* __restrict__ b1, const float* __restrict__ r1,
                         unsigned short* __restrict__ Wt) {
    int idx = blockIdx.x * 256 + threadIdx.x;
    if (idx >= 2 * 64 * 192) return;
    int layer = idx / (64 * 192);
    int rem = idx - layer * 64 * 192;
    int o = rem / 192, k = rem - o * 192;
    const float* bases = layer ? b1 : b0;
    const float* root  = layer ? r1 : r0;
    float w = (k < 64)  ? bases[(size_t)k * HH + o]
            : (k < 128) ? bases[(size_t)HH * HH + (size_t)(k - 64) * HH + o]
                        : root[(size_t)(k - 128) * HH + o];
    __half hv = __float2half_rn(w);
    Wt[idx] = *(unsigned short*)&hv;
}

// ---------------- fused layer: group-per-node gather into LDS, then MFMA GEMM ----------------
// Block = 64 dst nodes, 4 waves. Phase 1: 16-lane group per node (4 nodes/wave concurrent),
// lane dq owns dims [dq*4,dq*4+4): full 128-B row per load instr, no shuffle fold,
// direct LDS store. epair prefetched 1 iteration ahead to overlap latencies.
// Phase 2: MFMA 16x16x32_f16, K=192 = [mix(128, LDS) | h_in(64, global fp16)].
__launch_bounds__(256)
__global__ void k_layer(const int* __restrict__ rowstart, const int2* __restrict__ epair,
                        const float* __restrict__ comp, const unsigned short* __restrict__ hH,
                        const unsigned short* __restrict__ Wt, const float* __restrict__ bias,
                        unsigned short* __restrict__ outH) {
    __shared__ float2 lut[8];
    __shared__ _Float16 mixs[64][MPITCH];
    int tid = threadIdx.x;
    int wave = tid >> 6;
    int lane = tid & 63;
    if (tid < 8) {
        int r = tid < RR ? tid : 0;
        lut[tid] = make_float2(comp[r * NBB + 0], comp[r * NBB + 1]);
    }
    __syncthreads();

    int n0 = blockIdx.x * 64;
    int g  = lane >> 4;          // node group 0..3
    int dq = lane & 15;          // dim quarter: dims [dq*4, dq*4+4)

    // ---- phase 1: 4 nodes per wave concurrently, 4 outer iterations ----
    for (int i = 0; i < 4; ++i) {
        int row = wave * 16 + i * 4 + g;
        int node = n0 + row;
        float4 m0 = make_float4(0.f, 0.f, 0.f, 0.f);
        float4 m1 = make_float4(0.f, 0.f, 0.f, 0.f);
        int beg = 0, end = 0;
        if (node < NN) { beg = rowstart[node]; end = rowstart[node + 1]; }
        int2 pa = (beg < end) ? epair[beg] : make_int2(0, 0);
        int2 pb = (beg + 1 < end) ? epair[beg + 1] : make_int2(0, 0);
        for (int j = beg; j < end; j += 2) {
            // prefetch next pair (independent of current hH loads)
            int2 qa = (j + 2 < end) ? epair[j + 2] : make_int2(0, 0);
            int2 qb = (j + 3 < end) ? epair[j + 3] : make_int2(0, 0);
            uint2 ua = *(const uint2*)&hH[(size_t)(pa.x >> 3) * HH + dq * 4];
            uint2 ub = *(const uint2*)&hH[(size_t)(pb.x >> 3) * HH + dq * 4];
            float2 a01 = __half22float2(*(__half2*)&ua.x);
            float2 a23 = __half22float2(*(__half2*)&ua.y);
            float2 b01 = __half22float2(*(__half2*)&ub.x);
            float2 b23 = __half22float2(*(__half2*)&ub.y);
            float2 ca = lut[pa.x & 7];
            float2 cb = lut[pb.x & 7];
            float na = __int_as_float(pa.y);
            float nb = __int_as_float(pb.y);
            float a0 = ca.x * na, a1 = ca.y * na;
            float b0 = cb.x * nb, b1 = cb.y * nb;
            m0.x += a0 * a01.x; m0.y += a0 * a01.y; m0.z += a0 * a23.x; m0.w += a0 * a23.y;
            m1.x += a1 * a01.x; m1.y += a1 * a01.y; m1.z += a1 * a23.x; m1.w += a1 * a23.y;
            m0.x += b0 * b01.x; m0.y += b0 * b01.y; m0.z += b0 * b23.x; m0.w += b0 * b23.y;
            m1.x += b1 * b01.x; m1.y += b1 * b01.y; m1.z += b1 * b23.x; m1.w += b1 * b23.y;
            pa = qa; pb = qb;
        }
        __half2 lo0 = __floats2half2_rn(m0.x, m0.y);
        __half2 hi0 = __floats2half2_rn(m0.z, m0.w);
        __half2 lo1 = __floats2half2_rn(m1.x, m1.y);
        __half2 hi1 = __floats2half2_rn(m1.z, m1.w);
        *(uint2*)&mixs[row][dq * 4]      = make_uint2(*(unsigned*)&lo0, *(unsigned*)&hi0);
        *(uint2*)&mixs[row][64 + dq * 4] = make_uint2(*(unsigned*)&lo1, *(unsigned*)&hi1);
    }
    __syncthreads();

    // ---- phase 2: MFMA ----
    int lm = lane & 15;
    int lk = (lane >> 4) * 8;
    int rowA = wave * 16 + lm;
    int nodeA = n0 + rowA;
    int nodeClamp = nodeA < NN ? nodeA : NN - 1;

    f32x4 acc0 = {}, acc1 = {}, acc2 = {}, acc3 = {};
#pragma unroll
    for (int ks = 0; ks < 6; ++ks) {
        f16x8 a;
        if (ks < 4) a = *(const f16x8*)&mixs[rowA][ks * 32 + lk];
        else        a = *(const f16x8*)&hH[(size_t)nodeClamp * HH + (ks - 4) * 32 + lk];
        f16x8 b0 = *(const f16x8*)&Wt[(size_t)(0 * 16 + lm) * 192 + ks * 32 + lk];
        f16x8 b1 = *(const f16x8*)&Wt[(size_t)(1 * 16 + lm) * 192 + ks * 32 + lk];
        f16x8 b2 = *(const f16x8*)&Wt[(size_t)(2 * 16 + lm) * 192 + ks * 32 + lk];
        f16x8 b3 = *(const f16x8*)&Wt[(size_t)(3 * 16 + lm) * 192 + ks * 32 + lk];
        acc0 = __builtin_amdgcn_mfma_f32_16x16x32_f16(a, b0, acc0, 0, 0, 0);
        acc1 = __builtin_amdgcn_mfma_f32_16x16x32_f16(a, b1, acc1, 0, 0, 0);
        acc2 = __builtin_amdgcn_mfma_f32_16x16x32_f16(a, b2, acc2, 0, 0, 0);
        acc3 = __builtin_amdgcn_mfma_f32_16x16x32_f16(a, b3, acc3, 0, 0, 0);
    }

    float bv0 = bias[0 * 16 + lm];
    float bv1 = bias[1 * 16 + lm];
    float bv2 = bias[2 * 16 + lm];
    float bv3 = bias[3 * 16 + lm];

    int nrow = n0 + wave * 16 + (lane >> 4) * 4;
#pragma unroll
    for (int j = 0; j < 4; ++j) {
        int node = nrow + j;
        if (node >= NN) continue;
        __half h0 = __float2half_rn(acc0[j] + bv0);
        __half h1 = __float2half_rn(acc1[j] + bv1);
        __half h2 = __float2half_rn(acc2[j] + bv2);
        __half h3 = __float2half_rn(acc3[j] + bv3);
        outH[(size_t)node * HH +  0 + lm] = *(unsigned short*)&h0;
        outH[(size_t)node * HH + 16 + lm] = *(unsigned short*)&h1;
        outH[(size_t)node * HH + 32 + lm] = *(unsigned short*)&h2;
        outH[(size_t)node * HH + 48 + lm] = *(unsigned short*)&h3;
    }
}

// ---------------- layer-2: W2 in LDS + fp16-input GEMV: xW2[n][r], h2 = root part + bias ----------------
__global__ void k_gemm2(const unsigned short* __restrict__ hH, const float* __restrict__ bases2,
                        const float* __restrict__ comp2, const float* __restrict__ root2,
                        const float* __restrict__ bias2, float* __restrict__ xW2,
                        float* __restrict__ h2) {
    __shared__ float sW2[6 * HH];
    int tid = threadIdx.x;
    for (int i = tid; i < 6 * HH; i += 256) {
        int c = i >> 6, k = i & 63;
        sW2[i] = (c < RR) ? (comp2[c * NBB + 0] * bases2[k] + comp2[c * NBB + 1] * bases2[HH + k])
                          : root2[k];
    }
    __syncthreads();
    int n = blockIdx.x * blockDim.x + tid;
    if (n >= NN) return;
    float hr[64];
#pragma unroll
    for (int q = 0; q < 16; q++) {
        uint2 u = *(const uint2*)&hH[(size_t)n * HH + q * 4];
        float2 lo = __half22float2(*(__half2*)&u.x);
        float2 hi = __half22float2(*(__half2*)&u.y);
        hr[q * 4 + 0] = lo.x; hr[q * 4 + 1] = lo.y; hr[q * 4 + 2] = hi.x; hr[q * 4 + 3] = hi.y;
    }
#pragma unroll
    for (int c = 0; c < 6; c++) {
        float acc = 0.f;
#pragma unroll
        for (int k = 0; k < 64; k++) acc += hr[k] * sW2[c * HH + k];
        if (c < RR) xW2[n * RR + c] = acc;
        else        h2[n] = acc + bias2[0];
    }
}

// ---------------- layer-2 gather + fused masked exp-sum ----------------
__global__ void k_gather2(const int* __restrict__ rowstart, const int2* __restrict__ epair,
                          const float* __restrict__ xW2, float* __restrict__ h2,
                          const int* __restrict__ absorbed, float* __restrict__ denom) {
    __shared__ float sdata[256];
    int tid = threadIdx.x;
    int n = blockIdx.x * blockDim.x + tid;
    float local = 0.f;
    if (n < NN) {
        int beg = rowstart[n], end = rowstart[n + 1];
        float acc = h2[n];
        for (int j = beg; j < end; ++j) {
            int2 p = epair[j];
            acc += __int_as_float(p.y) * xW2[(p.x >> 3) * RR + (p.x & 7)];
        }
        h2[n] = acc;
        if (!absorbed[n]) local = expf(acc);
    }
    sdata[tid] = local;
    __syncthreads();
    for (int s = 128; s > 0; s >>= 1) {
        if (tid < s) sdata[tid] += sdata[tid + s];
        __syncthreads();
    }
    if (tid == 0) atomicAdd(denom, sdata[0]);
}

// ---------------- final normalize ----------------
__global__ void k_final(const float* __restrict__ h2, const int* __restrict__ absorbed,
                        const float* __restrict__ denom, float* __restrict__ out) {
    int n = blockIdx.x * blockDim.x + threadIdx.x;
    if (n >= NN) return;
    out[n] = absorbed[n] ? 0.f : expf(h2[n]) / denom[0];
}

extern "C" void kernel_launch(void* const* d_in, const int* in_sizes, int n_in,
                              void* d_out, int out_size, void* d_ws, size_t ws_size,
                              hipStream_t stream) {
    const int* x     = (const int*)d_in[0];
    const int* ei    = (const int*)d_in[1];
    const int* et    = (const int*)d_in[2];
    const int* order = (const int*)d_in[3];
    const float* emb = (const float*)d_in[4];
    const float* bases[3] = {(const float*)d_in[5], (const float*)d_in[9],  (const float*)d_in[13]};
    const float* comp[3]  = {(const float*)d_in[6], (const float*)d_in[10], (const float*)d_in[14]};
    const float* root[3]  = {(const float*)d_in[7], (const float*)d_in[11], (const float*)d_in[15]};
    const float* bias[3]  = {(const float*)d_in[8], (const float*)d_in[12], (const float*)d_in[16]};
    const int* srcp = ei;
    const int* dstp = ei + NE;

    char* w = (char*)d_ws;
    size_t off = 0;
    auto alloc = [&](size_t bytes) -> void* {
        void* p = w + off;
        off = (off + bytes + 255) & ~(size_t)255;
        return p;
    };
    unsigned short* hHa = (unsigned short*)alloc((size_t)NN * HH * 2);
    unsigned short* hHb = (unsigned short*)alloc((size_t)NN * HH * 2);
    float* xW2      = (float*)alloc((size_t)NN * RR * 4);
    float* h2       = (float*)alloc((size_t)NN * 4);
    int*   absorbed = (int*)alloc((size_t)NN * 4);
    int*   rowstart = (int*)alloc((size_t)(NN + 1) * 4);
    int*   gbcnt    = (int*)alloc((size_t)NBK * 4);
    int*   bcur     = (int*)alloc((size_t)NBK * 4);
    int*   bbase    = (int*)alloc((size_t)(NBK + 1) * 4);
    unsigned int* ebuf = (unsigned int*)alloc((size_t)NE * 4);
    int2*  epair    = (int2*)alloc((size_t)NE * 8);
    unsigned short* Wt = (unsigned short*)alloc((size_t)2 * 64 * 192 * 2);
    float* denom    = (float*)alloc(256);

    // init (also zeroes gbcnt/bcur/absorbed/denom)
    k_init_h<<<(NN * 16 + 255) / 256, 256, 0, stream>>>(x, (const float4*)emb, hHa,
                                                        gbcnt, bcur, absorbed, denom);
    k_pe<<<(KK * 16 + 255) / 256, 256, 0, stream>>>(order, hHa, absorbed);

    // bucketed CSR build + weight transpose
    k_bcnt<<<256, 256, 0, stream>>>(dstp, gbcnt);
    k_makeWt<<<96, 256, 0, stream>>>(bases[0], root[0], bases[1], root[1], Wt);
    k_bscan<<<1, 512, 0, stream>>>(gbcnt, bbase);
    k_bplace<<<256, 256, 0, stream>>>(srcp, dstp, et, bbase, bcur, ebuf);
    k_bsort<<<NBK, 256, 0, stream>>>(ebuf, bbase, epair, rowstart);

    int glayer = (NN + 63) / 64;

    // layer 0: hHa -> hHb ; layer 1: hHb -> hHa
    k_layer<<<glayer, 256, 0, stream>>>(rowstart, epair, comp[0], hHa, Wt, bias[0], hHb);
    k_layer<<<glayer, 256, 0, stream>>>(rowstart, epair, comp[1], hHb, Wt + (size_t)64 * 192,
                                        bias[1], hHa);

    // layer 2: hHa -> h2 (W2 built in-kernel; gather fused with exp-reduce)
    k_gemm2<<<(NN + 255) / 256, 256, 0, stream>>>(hHa, bases[2], comp[2], root[2], bias[2], xW2, h2);
    k_gather2<<<(NN + 255) / 256, 256, 0, stream>>>(rowstart, epair, xW2, h2, absorbed, denom);

    k_final<<<(NN + 255) / 256, 256, 0, stream>>>(h2, absorbed, denom, (float*)d_out);
}

// Round 13
// 214.544 us; speedup vs baseline: 1.7420x; 1.0290x over previous
//
#include <hip/hip_runtime.h>
#include <hip/hip_fp16.h>
#include <math.h>

#define NN 100000
#define NE 1600000
#define RR 5
#define HH 64
#define KK 10000
#define NBB 2
#define NBK 391            // dst buckets of 256 nodes: ceil(100000/256)
#define EPB 6250           // edges per block in bucket passes (256 blocks)
#define BCAP 8192          // pass-2 LDS capacity per bucket (mean 4096, std 64)
#define MPITCH 136         // LDS mix row pitch in halves (272 B = 17*16 -> b128-aligned rows)

typedef _Float16 f16x8 __attribute__((ext_vector_type(8)));
typedef float f32x4 __attribute__((ext_vector_type(4)));

// ---------------- h init: hH[n] = fp16(emb[x[n]]) + zero scratch ----------------
__global__ void k_init_h(const int* __restrict__ x, const float4* __restrict__ emb4,
                         unsigned short* __restrict__ hH,
                         int* __restrict__ gbcnt, int* __restrict__ bcur,
                         int* __restrict__ absorbed, float* __restrict__ denom) {
    int idx = blockIdx.x * blockDim.x + threadIdx.x;
    if (idx >= NN * 16) return;
    int n = idx >> 4;
    int q = idx & 15;
    float4 v = emb4[x[n] * 16 + q];
    __half2 lo = __floats2half2_rn(v.x, v.y);
    __half2 hi = __floats2half2_rn(v.z, v.w);
    *(uint2*)&hH[(size_t)n * HH + q * 4] = make_uint2(*(unsigned*)&lo, *(unsigned*)&hi);
    if (idx < NBK) { gbcnt[idx] = 0; bcur[idx] = 0; }
    if (idx == NBK) denom[0] = 0.f;
    if (idx < NN) absorbed[idx] = 0;
}

// ---------------- PE add + absorbed mask (fp16 in-place; node_order entries distinct) ----------------
__global__ void k_pe(const int* __restrict__ order, unsigned short* __restrict__ hH,
                     int* __restrict__ absorbed) {
    int idx = blockIdx.x * blockDim.x + threadIdx.x;
    if (idx >= KK * 16) return;
    int t = idx >> 4;
    int q = idx & 15;
    int node = order[t];
    float v = (float)sin((double)(t + 1));   // exact arg reduction, matches np
    uint2 u = *(uint2*)&hH[(size_t)node * HH + q * 4];
    float2 lo = __half22float2(*(__half2*)&u.x);
    float2 hi = __half22float2(*(__half2*)&u.y);
    __half2 nlo = __floats2half2_rn(lo.x + v, lo.y + v);
    __half2 nhi = __floats2half2_rn(hi.x + v, hi.y + v);
    *(uint2*)&hH[(size_t)node * HH + q * 4] = make_uint2(*(unsigned*)&nlo, *(unsigned*)&nhi);
    if (q == 0) absorbed[node] = 1;
}

// ---------------- bucket pass 1a: per-block LDS histogram over dst>>8 ----------------
__global__ void k_bcnt(const int* __restrict__ dst, int* __restrict__ gbcnt) {
    __shared__ int hist[NBK];
    int tid = threadIdx.x;
    for (int i = tid; i < NBK; i += 256) hist[i] = 0;
    __syncthreads();
    int e0 = blockIdx.x * EPB;
    int e1 = e0 + EPB < NE ? e0 + EPB : NE;
    for (int e = e0 + tid; e < e1; e += 256)
        atomicAdd(&hist[dst[e] >> 8], 1);
    __syncthreads();
    for (int i = tid; i < NBK; i += 256)
        if (hist[i]) atomicAdd(&gbcnt[i], hist[i]);
}

// ---------------- bucket pass 1b: exclusive scan of 391 bucket sizes ----------------
__global__ void k_bscan(const int* __restrict__ gbcnt, int* __restrict__ bbase) {
    __shared__ int s[512];
    int tid = threadIdx.x;
    int v = (tid < NBK) ? gbcnt[tid] : 0;
    s[tid] = v;
    __syncthreads();
#pragma unroll
    for (int off = 1; off < 512; off <<= 1) {
        int t = (tid >= off) ? s[tid - off] : 0;
        __syncthreads();
        s[tid] += t;
        __syncthreads();
    }
    if (tid < NBK) bbase[tid] = s[tid] - v;
    if (tid == NBK - 1) bbase[NBK] = s[tid];
}

// ---------------- bucket pass 1c: block-span reservation + packed scatter ----------------
// entry = (dst&255)<<20 | src<<3 | rel   (src<2^17, rel<2^3)
__global__ void k_bplace(const int* __restrict__ src, const int* __restrict__ dst,
                         const int* __restrict__ et, const int* __restrict__ bbase,
                         int* __restrict__ bcur, unsigned int* __restrict__ ebuf) {
    __shared__ int hist[NBK];
    __shared__ int lbase[NBK];
    __shared__ int lcur[NBK];
    int tid = threadIdx.x;
    for (int i = tid; i < NBK; i += 256) { hist[i] = 0; lcur[i] = 0; }
    __syncthreads();
    int e0 = blockIdx.x * EPB;
    int e1 = e0 + EPB < NE ? e0 + EPB : NE;
    for (int e = e0 + tid; e < e1; e += 256)
        atomicAdd(&hist[dst[e] >> 8], 1);
    __syncthreads();
    for (int i = tid; i < NBK; i += 256)
        if (hist[i]) lbase[i] = bbase[i] + atomicAdd(&bcur[i], hist[i]);
    __syncthreads();
    for (int e = e0 + tid; e < e1; e += 256) {
        int d = dst[e];
        int b = d >> 8;
        int r = atomicAdd(&lcur[b], 1);
        ebuf[lbase[b] + r] = ((unsigned)(d & 255) << 20) | ((unsigned)src[e] << 3) | (unsigned)et[e];
    }
}

// ---------------- bucket pass 2: per-bucket exact sort + norm + rowstart + epair ----------------
__launch_bounds__(256)
__global__ void k_bsort(const unsigned int* __restrict__ ebuf, const int* __restrict__ bbase,
                        int2* __restrict__ epair, int* __restrict__ rowstart) {
    __shared__ unsigned int el[BCAP];
    __shared__ int cnt5[256 * RR];
    __shared__ float norm5[256 * RR];
    __shared__ int dcur[256];
    __shared__ int s[256];
    int tid = threadIdx.x;
    int b = blockIdx.x;
    int base = bbase[b];
    int sz = bbase[b + 1] - base;
    if (sz > BCAP) sz = BCAP;   // statistically impossible; prevents corruption

    for (int i = tid; i < sz; i += 256) el[i] = ebuf[base + i];
    for (int i = tid; i < 256 * RR; i += 256) cnt5[i] = 0;
    __syncthreads();
    for (int i = tid; i < sz; i += 256) {
        unsigned int e = el[i];
        atomicAdd(&cnt5[(e >> 20) * RR + (e & 7)], 1);
    }
    __syncthreads();
    // per-dst degree + block scan (exclusive)
    int deg = 0;
#pragma unroll
    for (int r = 0; r < RR; r++) deg += cnt5[tid * RR + r];
    s[tid] = deg;
    dcur[tid] = 0;
    __syncthreads();
#pragma unroll
    for (int off = 1; off < 256; off <<= 1) {
        int t = (tid >= off) ? s[tid - off] : 0;
        __syncthreads();
        s[tid] += t;
        __syncthreads();
    }
    int rs = s[tid] - deg;      // exclusive scan
    for (int i = tid; i < 256 * RR; i += 256) {
        int c = cnt5[i];
        norm5[i] = 1.0f / (float)(c > 1 ? c : 1);
    }
    __syncthreads();
    // placement into global epair (one CU -> L2-local writes)
    for (int i = tid; i < sz; i += 256) {
        unsigned int e = el[i];
        int d8 = e >> 20;
        int rk = atomicAdd(&dcur[d8], 1);
        int pos = base + (s[d8] - (cnt5[d8 * RR + 0] + cnt5[d8 * RR + 1] + cnt5[d8 * RR + 2]
                                   + cnt5[d8 * RR + 3] + cnt5[d8 * RR + 4])) + rk;
        epair[pos] = make_int2((int)(e & 0xFFFFFu), __float_as_int(norm5[d8 * RR + (e & 7)]));
    }
    // rowstart
    int d = b * 256 + tid;
    if (d < NN) rowstart[d] = base + rs;
    if (b == 0 && tid == 0) rowstart[NN] = NE;
}

// ---------------- Wt build: fp16 W^T for both layers: Wt[layer][o][k], k in [0,192) ----------------
__global__ void k_makeWt(const float* __restrict__ b0, const float* __restrict__ r0,
                         const float* __restrict__ b1, const float* __restrict__ r1,
                         unsigned short* __restrict__ Wt) {
    int idx = blockIdx.x * 256 + threadIdx.x;
    if (idx >= 2 * 64 * 192) return;
    int layer = idx / (64 * 192);
    int rem = idx - layer * 64 * 192;
    int o = rem / 192, k = rem - o * 192;
    const float* bases = layer ? b1 : b0;
    const float* root  = layer ? r1 : r0;
    float w = (k < 64)  ? bases[(size_t)k * HH + o]
            : (k < 128) ? bases[(size_t)HH * HH + (size_t)(k - 64) * HH + o]
                        : root[(size_t)(k - 128) * HH + o];
    __half hv = __float2half_rn(w);
    Wt[idx] = *(unsigned short*)&hv;
}

// ---------------- fused layer: 8-chain gather into LDS, then MFMA GEMM ----------------
// Block = 64 dst nodes, 4 waves. Phase 1: 8-lane group per node (8 concurrent nodes/wave),
// lane dq owns dims [dq*8,dq*8+8): one uint4 (16B) load per edge per lane; edge loop
// unrolled x4 with loads batched before FMAs -> 32 loads in flight per wave.
// Phase 2: MFMA 16x16x32_f16, K=192 = [mix(128, LDS) | h_in(64, global fp16)].
__launch_bounds__(256)
__global__ void k_layer(const int* __restrict__ rowstart, const int2* __restrict__ epair,
                        const float* __restrict__ comp, const unsigned short* __restrict__ hH,
                        const unsigned short* __restrict__ Wt, const float* __restrict__ bias,
                        unsigned short* __restrict__ outH) {
    __shared__ float2 lut[8];
    __shared__ _Float16 mixs[64][MPITCH];
    int tid = threadIdx.x;
    int wave = tid >> 6;
    int lane = tid & 63;
    if (tid < 8) {
        int r = tid < RR ? tid : 0;
        lut[tid] = make_float2(comp[r * NBB + 0], comp[r * NBB + 1]);
    }
    __syncthreads();

    int n0 = blockIdx.x * 64;
    int g  = lane >> 3;          // node subgroup 0..7
    int dq = lane & 7;           // dim octet: dims [dq*8, dq*8+8)

    // ---- phase 1: 8 nodes per wave concurrently, 2 outer iterations ----
    for (int i = 0; i < 2; ++i) {
        int row = wave * 16 + i * 8 + g;
        int node = n0 + row;
        float m0[8] = {}, m1[8] = {};
        int beg = 0, end = 0;
        if (node < NN) { beg = rowstart[node]; end = rowstart[node + 1]; }
        int2 p[4];
#pragma unroll
        for (int u = 0; u < 4; ++u) p[u] = (beg + u < end) ? epair[beg + u] : make_int2(0, 0);
        for (int j = beg; j < end; j += 4) {
            int2 q[4];
#pragma unroll
            for (int u = 0; u < 4; ++u)
                q[u] = (j + 4 + u < end) ? epair[j + 4 + u] : make_int2(0, 0);
            uint4 ua[4];
#pragma unroll
            for (int u = 0; u < 4; ++u)
                ua[u] = *(const uint4*)&hH[(size_t)(p[u].x >> 3) * HH + dq * 8];
#pragma unroll
            for (int u = 0; u < 4; ++u) {
                float2 cc = lut[p[u].x & 7];
                float nv = __int_as_float(p[u].y);
                float a0 = cc.x * nv, a1 = cc.y * nv;
                float2 f;
                f = __half22float2(*(__half2*)&ua[u].x);
                m0[0] += a0 * f.x; m0[1] += a0 * f.y; m1[0] += a1 * f.x; m1[1] += a1 * f.y;
                f = __half22float2(*(__half2*)&ua[u].y);
                m0[2] += a0 * f.x; m0[3] += a0 * f.y; m1[2] += a1 * f.x; m1[3] += a1 * f.y;
                f = __half22float2(*(__half2*)&ua[u].z);
                m0[4] += a0 * f.x; m0[5] += a0 * f.y; m1[4] += a1 * f.x; m1[5] += a1 * f.y;
                f = __half22float2(*(__half2*)&ua[u].w);
                m0[6] += a0 * f.x; m0[7] += a0 * f.y; m1[6] += a1 * f.x; m1[7] += a1 * f.y;
            }
#pragma unroll
            for (int u = 0; u < 4; ++u) p[u] = q[u];
        }
        __half2 a01 = __floats2half2_rn(m0[0], m0[1]);
        __half2 a23 = __floats2half2_rn(m0[2], m0[3]);
        __half2 a45 = __floats2half2_rn(m0[4], m0[5]);
        __half2 a67 = __floats2half2_rn(m0[6], m0[7]);
        *(uint4*)&mixs[row][dq * 8] =
            make_uint4(*(unsigned*)&a01, *(unsigned*)&a23, *(unsigned*)&a45, *(unsigned*)&a67);
        __half2 b01 = __floats2half2_rn(m1[0], m1[1]);
        __half2 b23 = __floats2half2_rn(m1[2], m1[3]);
        __half2 b45 = __floats2half2_rn(m1[4], m1[5]);
        __half2 b67 = __floats2half2_rn(m1[6], m1[7]);
        *(uint4*)&mixs[row][64 + dq * 8] =
            make_uint4(*(unsigned*)&b01, *(unsigned*)&b23, *(unsigned*)&b45, *(unsigned*)&b67);
    }
    __syncthreads();

    // ---- phase 2: MFMA ----
    int lm = lane & 15;
    int lk = (lane >> 4) * 8;
    int rowA = wave * 16 + lm;
    int nodeA = n0 + rowA;
    int nodeClamp = nodeA < NN ? nodeA : NN - 1;

    f32x4 acc0 = {}, acc1 = {}, acc2 = {}, acc3 = {};
#pragma unroll
    for (int ks = 0; ks < 6; ++ks) {
        f16x8 a;
        if (ks < 4) a = *(const f16x8*)&mixs[rowA][ks * 32 + lk];
        else        a = *(const f16x8*)&hH[(size_t)nodeClamp * HH + (ks - 4) * 32 + lk];
        f16x8 b0 = *(const f16x8*)&Wt[(size_t)(0 * 16 + lm) * 192 + ks * 32 + lk];
        f16x8 b1 = *(const f16x8*)&Wt[(size_t)(1 * 16 + lm) * 192 + ks * 32 + lk];
        f16x8 b2 = *(const f16x8*)&Wt[(size_t)(2 * 16 + lm) * 192 + ks * 32 + lk];
        f16x8 b3 = *(const f16x8*)&Wt[(size_t)(3 * 16 + lm) * 192 + ks * 32 + lk];
        acc0 = __builtin_amdgcn_mfma_f32_16x16x32_f16(a, b0, acc0, 0, 0, 0);
        acc1 = __builtin_amdgcn_mfma_f32_16x16x32_f16(a, b1, acc1, 0, 0, 0);
        acc2 = __builtin_amdgcn_mfma_f32_16x16x32_f16(a, b2, acc2, 0, 0, 0);
        acc3 = __builtin_amdgcn_mfma_f32_16x16x32_f16(a, b3, acc3, 0, 0, 0);
    }

    float bv0 = bias[0 * 16 + lm];
    float bv1 = bias[1 * 16 + lm];
    float bv2 = bias[2 * 16 + lm];
    float bv3 = bias[3 * 16 + lm];

    int nrow = n0 + wave * 16 + (lane >> 4) * 4;
#pragma unroll
    for (int j = 0; j < 4; ++j) {
        int node = nrow + j;
        if (node >= NN) continue;
        __half h0 = __float2half_rn(acc0[j] + bv0);
        __half h1 = __float2half_rn(acc1[j] + bv1);
        __half h2 = __float2half_rn(acc2[j] + bv2);
        __half h3 = __float2half_rn(acc3[j] + bv3);
        outH[(size_t)node * HH +  0 + lm] = *(unsigned short*)&h0;
        outH[(size_t)node * HH + 16 + lm] = *(unsigned short*)&h1;
        outH[(size_t)node * HH + 32 + lm] = *(unsigned short*)&h2;
        outH[(size_t)node * HH + 48 + lm] = *(unsigned short*)&h3;
    }
}

// ---------------- layer-2: W2 in LDS + fp16-input GEMV: xW2[n][r], h2 = root part + bias ----------------
__global__ void k_gemm2(const unsigned short* __restrict__ hH, const float* __restrict__ bases2,
                        const float* __restrict__ comp2, const float* __restrict__ root2,
                        const float* __restrict__ bias2, float* __restrict__ xW2,
                        float* __restrict__ h2) {
    __shared__ float sW2[6 * HH];
    int tid = threadIdx.x;
    for (int i = tid; i < 6 * HH; i += 256) {
        int c = i >> 6, k = i & 63;
        sW2[i] = (c < RR) ? (comp2[c * NBB + 0] * bases2[k] + comp2[c * NBB + 1] * bases2[HH + k])
                          : root2[k];
    }
    __syncthreads();
    int n = blockIdx.x * blockDim.x + tid;
    if (n >= NN) return;
    float hr[64];
#pragma unroll
    for (int q = 0; q < 16; q++) {
        uint2 u = *(const uint2*)&hH[(size_t)n * HH + q * 4];
        float2 lo = __half22float2(*(__half2*)&u.x);
        float2 hi = __half22float2(*(__half2*)&u.y);
        hr[q * 4 + 0] = lo.x; hr[q * 4 + 1] = lo.y; hr[q * 4 + 2] = hi.x; hr[q * 4 + 3] = hi.y;
    }
#pragma unroll
    for (int c = 0; c < 6; c++) {
        float acc = 0.f;
#pragma unroll
        for (int k = 0; k < 64; k++) acc += hr[k] * sW2[c * HH + k];
        if (c < RR) xW2[n * RR + c] = acc;
        else        h2[n] = acc + bias2[0];
    }
}

// ---------------- layer-2 gather + fused masked exp-sum ----------------
__global__ void k_gather2(const int* __restrict__ rowstart, const int2* __restrict__ epair,
                          const float* __restrict__ xW2, float* __restrict__ h2,
                          const int* __restrict__ absorbed, float* __restrict__ denom) {
    __shared__ float sdata[256];
    int tid = threadIdx.x;
    int n = blockIdx.x * blockDim.x + tid;
    float local = 0.f;
    if (n < NN) {
        int beg = rowstart[n], end = rowstart[n + 1];
        float acc = h2[n];
        for (int j = beg; j < end; ++j) {
            int2 p = epair[j];
            acc += __int_as_float(p.y) * xW2[(p.x >> 3) * RR + (p.x & 7)];
        }
        h2[n] = acc;
        if (!absorbed[n]) local = expf(acc);
    }
    sdata[tid] = local;
    __syncthreads();
    for (int s = 128; s > 0; s >>= 1) {
        if (tid < s) sdata[tid] += sdata[tid + s];
        __syncthreads();
    }
    if (tid == 0) atomicAdd(denom, sdata[0]);
}

// ---------------- final normalize ----------------
__global__ void k_final(const float* __restrict__ h2, const int* __restrict__ absorbed,
                        const float* __restrict__ denom, float* __restrict__ out) {
    int n = blockIdx.x * blockDim.x + threadIdx.x;
    if (n >= NN) return;
    out[n] = absorbed[n] ? 0.f : expf(h2[n]) / denom[0];
}

extern "C" void kernel_launch(void* const* d_in, const int* in_sizes, int n_in,
                              void* d_out, int out_size, void* d_ws, size_t ws_size,
                              hipStream_t stream) {
    const int* x     = (const int*)d_in[0];
    const int* ei    = (const int*)d_in[1];
    const int* et    = (const int*)d_in[2];
    const int* order = (const int*)d_in[3];
    const float* emb = (const float*)d_in[4];
    const float* bases[3] = {(const float*)d_in[5], (const float*)d_in[9],  (const float*)d_in[13]};
    const float* comp[3]  = {(const float*)d_in[6], (const float*)d_in[10], (const float*)d_in[14]};
    const float* root[3]  = {(const float*)d_in[7], (const float*)d_in[11], (const float*)d_in[15]};
    const float* bias[3]  = {(const float*)d_in[8], (const float*)d_in[12], (const float*)d_in[16]};
    const int* srcp = ei;
    const int* dstp = ei + NE;

    char* w = (char*)d_ws;
    size_t off = 0;
    auto alloc = [&](size_t bytes) -> void* {
        void* p = w + off;
        off = (off + bytes + 255) & ~(size_t)255;
        return p;
    };
    unsigned short* hHa = (unsigned short*)alloc((size_t)NN * HH * 2);
    unsigned short* hHb = (unsigned short*)alloc((size_t)NN * HH * 2);
    float* xW2      = (float*)alloc((size_t)NN * RR * 4);
    float* h2       = (float*)alloc((size_t)NN * 4);
    int*   absorbed = (int*)alloc((size_t)NN * 4);
    int*   rowstart = (int*)alloc((size_t)(NN + 1) * 4);
    int*   gbcnt    = (int*)alloc((size_t)NBK * 4);
    int*   bcur     = (int*)alloc((size_t)NBK * 4);
    int*   bbase    = (int*)alloc((size_t)(NBK + 1) * 4);
    unsigned int* ebuf = (unsigned int*)alloc((size_t)NE * 4);
    int2*  epair    = (int2*)alloc((size_t)NE * 8);
    unsigned short* Wt = (unsigned short*)alloc((size_t)2 * 64 * 192 * 2);
    float* denom    = (float*)alloc(256);

    // init (also zeroes gbcnt/bcur/absorbed/denom)
    k_init_h<<<(NN * 16 + 255) / 256, 256, 0, stream>>>(x, (const float4*)emb, hHa,
                                                        gbcnt, bcur, absorbed, denom);
    k_pe<<<(KK * 16 + 255) / 256, 256, 0, stream>>>(order, hHa, absorbed);

    // bucketed CSR build + weight transpose
    k_bcnt<<<256, 256, 0, stream>>>(dstp, gbcnt);
    k_makeWt<<<96, 256, 0, stream>>>(bases[0], root[0], bases[1], root[1], Wt);
    k_bscan<<<1, 512, 0, stream>>>(gbcnt, bbase);
    k_bplace<<<256, 256, 0, stream>>>(srcp, dstp, et, bbase, bcur, ebuf);
    k_bsort<<<NBK, 256, 0, stream>>>(ebuf, bbase, epair, rowstart);

    int glayer = (NN + 63) / 64;

    // layer 0: hHa -> hHb ; layer 1: hHb -> hHa
    k_layer<<<glayer, 256, 0, stream>>>(rowstart, epair, comp[0], hHa, Wt, bias[0], hHb);
    k_layer<<<glayer, 256, 0, stream>>>(rowstart, epair, comp[1], hHb, Wt + (size_t)64 * 192,
                                        bias[1], hHa);

    // layer 2: hHa -> h2 (W2 built in-kernel; gather fused with exp-reduce)
    k_gemm2<<<(NN + 255) / 256, 256, 0, stream>>>(hHa, bases[2], comp[2], root[2], bias[2], xW2, h2);
    k_gather2<<<(NN + 255) / 256, 256, 0, stream>>>(rowstart, epair, xW2, h2, absorbed, denom);

    k_final<<<(NN + 255) / 256, 256, 0, stream>>>(h2, absorbed, denom, (float*)d_out);
}

// Round 14
// 208.589 us; speedup vs baseline: 1.7918x; 1.0285x over previous
//
#include <hip/hip_runtime.h>
#include <hip/hip_fp16.h>
#include <math.h>

#define NN 100000
#define NE 1600000
#define RR 5
#define HH 64
#define KK 10000
#define NBB 2
#define NBK 391            // dst buckets of 256 nodes: ceil(100000/256)
#define EPB 6250           // edges per block in bucket passes (256 blocks)
#define BCAP 8192          // pass-2 LDS capacity per bucket (mean 4096, std 64)
#define MPITCH 136         // LDS mix row pitch in halves (272 B = 17*16 -> b128-aligned rows)

typedef _Float16 f16x8 __attribute__((ext_vector_type(8)));
typedef float f32x4 __attribute__((ext_vector_type(4)));

// ---------------- h init: hH[n] = fp16(emb[x[n]]) + zero scratch ----------------
__global__ void k_init_h(const int* __restrict__ x, const float4* __restrict__ emb4,
                         unsigned short* __restrict__ hH,
                         int* __restrict__ gbcnt, int* __restrict__ bcur,
                         int* __restrict__ absorbed, float* __restrict__ denom) {
    int idx = blockIdx.x * blockDim.x + threadIdx.x;
    if (idx >= NN * 16) return;
    int n = idx >> 4;
    int q = idx & 15;
    float4 v = emb4[x[n] * 16 + q];
    __half2 lo = __floats2half2_rn(v.x, v.y);
    __half2 hi = __floats2half2_rn(v.z, v.w);
    *(uint2*)&hH[(size_t)n * HH + q * 4] = make_uint2(*(unsigned*)&lo, *(unsigned*)&hi);
    if (idx < NBK) { gbcnt[idx] = 0; bcur[idx] = 0; }
    if (idx == NBK) denom[0] = 0.f;
    if (idx < NN) absorbed[idx] = 0;
}

// ---------------- PE add + absorbed mask (fp16 in-place; node_order entries distinct) ----------------
__global__ void k_pe(const int* __restrict__ order, unsigned short* __restrict__ hH,
                     int* __restrict__ absorbed) {
    int idx = blockIdx.x * blockDim.x + threadIdx.x;
    if (idx >= KK * 16) return;
    int t = idx >> 4;
    int q = idx & 15;
    int node = order[t];
    float v = (float)sin((double)(t + 1));   // exact arg reduction, matches np
    uint2 u = *(uint2*)&hH[(size_t)node * HH + q * 4];
    float2 lo = __half22float2(*(__half2*)&u.x);
    float2 hi = __half22float2(*(__half2*)&u.y);
    __half2 nlo = __floats2half2_rn(lo.x + v, lo.y + v);
    __half2 nhi = __floats2half2_rn(hi.x + v, hi.y + v);
    *(uint2*)&hH[(size_t)node * HH + q * 4] = make_uint2(*(unsigned*)&nlo, *(unsigned*)&nhi);
    if (q == 0) absorbed[node] = 1;
}

// ---------------- bucket pass 1a: per-block LDS histogram over dst>>8 ----------------
__global__ void k_bcnt(const int* __restrict__ dst, int* __restrict__ gbcnt) {
    __shared__ int hist[NBK];
    int tid = threadIdx.x;
    for (int i = tid; i < NBK; i += 256) hist[i] = 0;
    __syncthreads();
    int e0 = blockIdx.x * EPB;
    int e1 = e0 + EPB < NE ? e0 + EPB : NE;
    for (int e = e0 + tid; e < e1; e += 256)
        atomicAdd(&hist[dst[e] >> 8], 1);
    __syncthreads();
    for (int i = tid; i < NBK; i += 256)
        if (hist[i]) atomicAdd(&gbcnt[i], hist[i]);
}

// ---------------- bucket pass 1b: exclusive scan of 391 bucket sizes ----------------
__global__ void k_bscan(const int* __restrict__ gbcnt, int* __restrict__ bbase) {
    __shared__ int s[512];
    int tid = threadIdx.x;
    int v = (tid < NBK) ? gbcnt[tid] : 0;
    s[tid] = v;
    __syncthreads();
#pragma unroll
    for (int off = 1; off < 512; off <<= 1) {
        int t = (tid >= off) ? s[tid - off] : 0;
        __syncthreads();
        s[tid] += t;
        __syncthreads();
    }
    if (tid < NBK) bbase[tid] = s[tid] - v;
    if (tid == NBK - 1) bbase[NBK] = s[tid];
}

// ---------------- bucket pass 1c: block-span reservation + packed scatter ----------------
// entry = (dst&255)<<20 | src<<3 | rel   (src<2^17, rel<2^3)
__global__ void k_bplace(const int* __restrict__ src, const int* __restrict__ dst,
                         const int* __restrict__ et, const int* __restrict__ bbase,
                         int* __restrict__ bcur, unsigned int* __restrict__ ebuf) {
    __shared__ int hist[NBK];
    __shared__ int lbase[NBK];
    __shared__ int lcur[NBK];
    int tid = threadIdx.x;
    for (int i = tid; i < NBK; i += 256) { hist[i] = 0; lcur[i] = 0; }
    __syncthreads();
    int e0 = blockIdx.x * EPB;
    int e1 = e0 + EPB < NE ? e0 + EPB : NE;
    for (int e = e0 + tid; e < e1; e += 256)
        atomicAdd(&hist[dst[e] >> 8], 1);
    __syncthreads();
    for (int i = tid; i < NBK; i += 256)
        if (hist[i]) lbase[i] = bbase[i] + atomicAdd(&bcur[i], hist[i]);
    __syncthreads();
    for (int e = e0 + tid; e < e1; e += 256) {
        int d = dst[e];
        int b = d >> 8;
        int r = atomicAdd(&lcur[b], 1);
        ebuf[lbase[b] + r] = ((unsigned)(d & 255) << 20) | ((unsigned)src[e] << 3) | (unsigned)et[e];
    }
}

// ---------------- bucket pass 2: per-bucket exact sort + norm + rowstart + epair ----------------
__launch_bounds__(256)
__global__ void k_bsort(const unsigned int* __restrict__ ebuf, const int* __restrict__ bbase,
                        int2* __restrict__ epair, int* __restrict__ rowstart) {
    __shared__ unsigned int el[BCAP];
    __shared__ int cnt5[256 * RR];
    __shared__ float norm5[256 * RR];
    __shared__ int dcur[256];
    __shared__ int s[256];
    int tid = threadIdx.x;
    int b = blockIdx.x;
    int base = bbase[b];
    int sz = bbase[b + 1] - base;
    if (sz > BCAP) sz = BCAP;   // statistically impossible; prevents corruption

    for (int i = tid; i < sz; i += 256) el[i] = ebuf[base + i];
    for (int i = tid; i < 256 * RR; i += 256) cnt5[i] = 0;
    __syncthreads();
    for (int i = tid; i < sz; i += 256) {
        unsigned int e = el[i];
        atomicAdd(&cnt5[(e >> 20) * RR + (e & 7)], 1);
    }
    __syncthreads();
    // per-dst degree + block scan (exclusive)
    int deg = 0;
#pragma unroll
    for (int r = 0; r < RR; r++) deg += cnt5[tid * RR + r];
    s[tid] = deg;
    dcur[tid] = 0;
    __syncthreads();
#pragma unroll
    for (int off = 1; off < 256; off <<= 1) {
        int t = (tid >= off) ? s[tid - off] : 0;
        __syncthreads();
        s[tid] += t;
        __syncthreads();
    }
    int rs = s[tid] - deg;      // exclusive scan
    for (int i = tid; i < 256 * RR; i += 256) {
        int c = cnt5[i];
        norm5[i] = 1.0f / (float)(c > 1 ? c : 1);
    }
    __syncthreads();
    // placement into global epair (one CU -> L2-local writes)
    for (int i = tid; i < sz; i += 256) {
        unsigned int e = el[i];
        int d8 = e >> 20;
        int rk = atomicAdd(&dcur[d8], 1);
        int pos = base + (s[d8] - (cnt5[d8 * RR + 0] + cnt5[d8 * RR + 1] + cnt5[d8 * RR + 2]
                                   + cnt5[d8 * RR + 3] + cnt5[d8 * RR + 4])) + rk;
        epair[pos] = make_int2((int)(e & 0xFFFFFu), __float_as_int(norm5[d8 * RR + (e & 7)]));
    }
    // rowstart
    int d = b * 256 + tid;
    if (d < NN) rowstart[d] = base + rs;
    if (b == 0 && tid == 0) rowstart[NN] = NE;
}

// ---------------- Wt build: fp16 W^T for both layers: Wt[layer][o][k], k in [0,192) ----------------
__global__ void k_makeWt(const float* __restrict__ b0, const float* __restrict__ r0,
                         const float* __restrict__ b1, const float* __restrict__ r1,
                         unsigned short* __restrict__ Wt) {
    int idx = blockIdx.x * 256 + threadIdx.x;
    if (idx >= 2 * 64 * 192) return;
    int layer = idx / (64 * 192);
    int rem = idx - layer * 64 * 192;
    int o = rem / 192, k = rem - o * 192;
    const float* bases = layer ? b1 : b0;
    const float* root  = layer ? r1 : r0;
    float w = (k < 64)  ? bases[(size_t)k * HH + o]
            : (k < 128) ? bases[(size_t)HH * HH + (size_t)(k - 64) * HH + o]
                        : root[(size_t)(k - 128) * HH + o];
    __half hv = __float2half_rn(w);
    Wt[idx] = *(unsigned short*)&hv;
}

// ---------------- fused layer: 8-chain x8-unroll gather into LDS, then MFMA GEMM ----------------
// Block = 64 dst nodes, 4 waves. Phase 1: 8-lane group per node (8 concurrent nodes/wave),
// lane dq owns dims [dq*8,dq*8+8): one uint4 (16B) load per edge per lane; edge loop
// unrolled x8 with loads batched before FMAs -> 64 loads in flight per wave.
// NO mid-kernel barrier: phase 2's A-frag reads only the same wave's mixs rows.
// Phase 2: MFMA 16x16x32_f16, K=192 = [mix(128, LDS) | h_in(64, global fp16)].
__launch_bounds__(256)
__global__ void k_layer(const int* __restrict__ rowstart, const int2* __restrict__ epair,
                        const float* __restrict__ comp, const unsigned short* __restrict__ hH,
                        const unsigned short* __restrict__ Wt, const float* __restrict__ bias,
                        unsigned short* __restrict__ outH) {
    __shared__ float2 lut[8];
    __shared__ _Float16 mixs[64][MPITCH];
    int tid = threadIdx.x;
    int wave = tid >> 6;
    int lane = tid & 63;
    if (tid < 8) {
        int r = tid < RR ? tid : 0;
        lut[tid] = make_float2(comp[r * NBB + 0], comp[r * NBB + 1]);
    }
    __syncthreads();     // lut ready (only cross-wave LDS dependency in the kernel)

    int n0 = blockIdx.x * 64;
    int g  = lane >> 3;          // node subgroup 0..7
    int dq = lane & 7;           // dim octet: dims [dq*8, dq*8+8)

    // ---- phase 1: 8 nodes per wave concurrently, 2 outer iterations, 8-edge batches ----
    for (int i = 0; i < 2; ++i) {
        int row = wave * 16 + i * 8 + g;
        int node = n0 + row;
        float m0[8] = {}, m1[8] = {};
        int beg = 0, end = 0;
        if (node < NN) { beg = rowstart[node]; end = rowstart[node + 1]; }
        int2 p[8];
#pragma unroll
        for (int u = 0; u < 8; ++u) p[u] = (beg + u < end) ? epair[beg + u] : make_int2(0, 0);
        for (int j = beg; j < end; j += 8) {
            int2 q[8];
#pragma unroll
            for (int u = 0; u < 8; ++u)
                q[u] = (j + 8 + u < end) ? epair[j + 8 + u] : make_int2(0, 0);
            uint4 ua[8];
#pragma unroll
            for (int u = 0; u < 8; ++u)
                ua[u] = *(const uint4*)&hH[(size_t)(p[u].x >> 3) * HH + dq * 8];
#pragma unroll
            for (int u = 0; u < 8; ++u) {
                float2 cc = lut[p[u].x & 7];
                float nv = __int_as_float(p[u].y);
                float a0 = cc.x * nv, a1 = cc.y * nv;
                float2 f;
                f = __half22float2(*(__half2*)&ua[u].x);
                m0[0] += a0 * f.x; m0[1] += a0 * f.y; m1[0] += a1 * f.x; m1[1] += a1 * f.y;
                f = __half22float2(*(__half2*)&ua[u].y);
                m0[2] += a0 * f.x; m0[3] += a0 * f.y; m1[2] += a1 * f.x; m1[3] += a1 * f.y;
                f = __half22float2(*(__half2*)&ua[u].z);
                m0[4] += a0 * f.x; m0[5] += a0 * f.y; m1[4] += a1 * f.x; m1[5] += a1 * f.y;
                f = __half22float2(*(__half2*)&ua[u].w);
                m0[6] += a0 * f.x; m0[7] += a0 * f.y; m1[6] += a1 * f.x; m1[7] += a1 * f.y;
            }
#pragma unroll
            for (int u = 0; u < 8; ++u) p[u] = q[u];
        }
        __half2 a01 = __floats2half2_rn(m0[0], m0[1]);
        __half2 a23 = __floats2half2_rn(m0[2], m0[3]);
        __half2 a45 = __floats2half2_rn(m0[4], m0[5]);
        __half2 a67 = __floats2half2_rn(m0[6], m0[7]);
        *(uint4*)&mixs[row][dq * 8] =
            make_uint4(*(unsigned*)&a01, *(unsigned*)&a23, *(unsigned*)&a45, *(unsigned*)&a67);
        __half2 b01 = __floats2half2_rn(m1[0], m1[1]);
        __half2 b23 = __floats2half2_rn(m1[2], m1[3]);
        __half2 b45 = __floats2half2_rn(m1[4], m1[5]);
        __half2 b67 = __floats2half2_rn(m1[6], m1[7]);
        *(uint4*)&mixs[row][64 + dq * 8] =
            make_uint4(*(unsigned*)&b01, *(unsigned*)&b23, *(unsigned*)&b45, *(unsigned*)&b67);
    }
    // no barrier: phase 2 A-frags read only this wave's rows (wave*16..wave*16+15)

    // ---- phase 2: MFMA ----
    int lm = lane & 15;
    int lk = (lane >> 4) * 8;
    int rowA = wave * 16 + lm;
    int nodeA = n0 + rowA;
    int nodeClamp = nodeA < NN ? nodeA : NN - 1;

    f32x4 acc0 = {}, acc1 = {}, acc2 = {}, acc3 = {};
#pragma unroll
    for (int ks = 0; ks < 6; ++ks) {
        f16x8 a;
        if (ks < 4) a = *(const f16x8*)&mixs[rowA][ks * 32 + lk];
        else        a = *(const f16x8*)&hH[(size_t)nodeClamp * HH + (ks - 4) * 32 + lk];
        f16x8 b0 = *(const f16x8*)&Wt[(size_t)(0 * 16 + lm) * 192 + ks * 32 + lk];
        f16x8 b1 = *(const f16x8*)&Wt[(size_t)(1 * 16 + lm) * 192 + ks * 32 + lk];
        f16x8 b2 = *(const f16x8*)&Wt[(size_t)(2 * 16 + lm) * 192 + ks * 32 + lk];
        f16x8 b3 = *(const f16x8*)&Wt[(size_t)(3 * 16 + lm) * 192 + ks * 32 + lk];
        acc0 = __builtin_amdgcn_mfma_f32_16x16x32_f16(a, b0, acc0, 0, 0, 0);
        acc1 = __builtin_amdgcn_mfma_f32_16x16x32_f16(a, b1, acc1, 0, 0, 0);
        acc2 = __builtin_amdgcn_mfma_f32_16x16x32_f16(a, b2, acc2, 0, 0, 0);
        acc3 = __builtin_amdgcn_mfma_f32_16x16x32_f16(a, b3, acc3, 0, 0, 0);
    }

    float bv0 = bias[0 * 16 + lm];
    float bv1 = bias[1 * 16 + lm];
    float bv2 = bias[2 * 16 + lm];
    float bv3 = bias[3 * 16 + lm];

    int nrow = n0 + wave * 16 + (lane >> 4) * 4;
#pragma unroll
    for (int j = 0; j < 4; ++j) {
        int node = nrow + j;
        if (node >= NN) continue;
        __half h0 = __float2half_rn(acc0[j] + bv0);
        __half h1 = __float2half_rn(acc1[j] + bv1);
        __half h2 = __float2half_rn(acc2[j] + bv2);
        __half h3 = __float2half_rn(acc3[j] + bv3);
        outH[(size_t)node * HH +  0 + lm] = *(unsigned short*)&h0;
        outH[(size_t)node * HH + 16 + lm] = *(unsigned short*)&h1;
        outH[(size_t)node * HH + 32 + lm] = *(unsigned short*)&h2;
        outH[(size_t)node * HH + 48 + lm] = *(unsigned short*)&h3;
    }
}

// ---------------- layer-2: W2 in LDS + fp16-input GEMV: xW2[n][r], h2 = root part + bias ----------------
__global__ void k_gemm2(const unsigned short* __restrict__ hH, const float* __restrict__ bases2,
                        const float* __restrict__ comp2, const float* __restrict__ root2,
                        const float* __restrict__ bias2, float* __restrict__ xW2,
                        float* __restrict__ h2) {
    __shared__ float sW2[6 * HH];
    int tid = threadIdx.x;
    for (int i = tid; i < 6 * HH; i += 256) {
        int c = i >> 6, k = i & 63;
        sW2[i] = (c < RR) ? (comp2[c * NBB + 0] * bases2[k] + comp2[c * NBB + 1] * bases2[HH + k])
                          : root2[k];
    }
    __syncthreads();
    int n = blockIdx.x * blockDim.x + tid;
    if (n >= NN) return;
    float hr[64];
#pragma unroll
    for (int q = 0; q < 16; q++) {
        uint2 u = *(const uint2*)&hH[(size_t)n * HH + q * 4];
        float2 lo = __half22float2(*(__half2*)&u.x);
        float2 hi = __half22float2(*(__half2*)&u.y);
        hr[q * 4 + 0] = lo.x; hr[q * 4 + 1] = lo.y; hr[q * 4 + 2] = hi.x; hr[q * 4 + 3] = hi.y;
    }
#pragma unroll
    for (int c = 0; c < 6; c++) {
        float acc = 0.f;
#pragma unroll
        for (int k = 0; k < 64; k++) acc += hr[k] * sW2[c * HH + k];
        if (c < RR) xW2[n * RR + c] = acc;
        else        h2[n] = acc + bias2[0];
    }
}

// ---------------- layer-2 gather + fused masked exp-sum ----------------
__global__ void k_gather2(const int* __restrict__ rowstart, const int2* __restrict__ epair,
                          const float* __restrict__ xW2, float* __restrict__ h2,
                          const int* __restrict__ absorbed, float* __restrict__ denom) {
    __shared__ float sdata[256];
    int tid = threadIdx.x;
    int n = blockIdx.x * blockDim.x + tid;
    float local = 0.f;
    if (n < NN) {
        int beg = rowstart[n], end = rowstart[n + 1];
        float acc = h2[n];
        for (int j = beg; j < end; ++j) {
            int2 p = epair[j];
            acc += __int_as_float(p.y) * xW2[(p.x >> 3) * RR + (p.x & 7)];
        }
        h2[n] = acc;
        if (!absorbed[n]) local = expf(acc);
    }
    sdata[tid] = local;
    __syncthreads();
    for (int s = 128; s > 0; s >>= 1) {
        if (tid < s) sdata[tid] += sdata[tid + s];
        __syncthreads();
    }
    if (tid == 0) atomicAdd(denom, sdata[0]);
}

// ---------------- final normalize ----------------
__global__ void k_final(const float* __restrict__ h2, const int* __restrict__ absorbed,
                        const float* __restrict__ denom, float* __restrict__ out) {
    int n = blockIdx.x * blockDim.x + threadIdx.x;
    if (n >= NN) return;
    out[n] = absorbed[n] ? 0.f : expf(h2[n]) / denom[0];
}

extern "C" void kernel_launch(void* const* d_in, const int* in_sizes, int n_in,
                              void* d_out, int out_size, void* d_ws, size_t ws_size,
                              hipStream_t stream) {
    const int* x     = (const int*)d_in[0];
    const int* ei    = (const int*)d_in[1];
    const int* et    = (const int*)d_in[2];
    const int* order = (const int*)d_in[3];
    const float* emb = (const float*)d_in[4];
    const float* bases[3] = {(const float*)d_in[5], (const float*)d_in[9],  (const float*)d_in[13]};
    const float* comp[3]  = {(const float*)d_in[6], (const float*)d_in[10], (const float*)d_in[14]};
    const float* root[3]  = {(const float*)d_in[7], (const float*)d_in[11], (const float*)d_in[15]};
    const float* bias[3]  = {(const float*)d_in[8], (const float*)d_in[12], (const float*)d_in[16]};
    const int* srcp = ei;
    const int* dstp = ei + NE;

    char* w = (char*)d_ws;
    size_t off = 0;
    auto alloc = [&](size_t bytes) -> void* {
        void* p = w + off;
        off = (off + bytes + 255) & ~(size_t)255;
        return p;
    };
    unsigned short* hHa = (unsigned short*)alloc((size_t)NN * HH * 2);
    unsigned short* hHb = (unsigned short*)alloc((size_t)NN * HH * 2);
    float* xW2      = (float*)alloc((size_t)NN * RR * 4);
    float* h2       = (float*)alloc((size_t)NN * 4);
    int*   absorbed = (int*)alloc((size_t)NN * 4);
    int*   rowstart = (int*)alloc((size_t)(NN + 1) * 4);
    int*   gbcnt    = (int*)alloc((size_t)NBK * 4);
    int*   bcur     = (int*)alloc((size_t)NBK * 4);
    int*   bbase    = (int*)alloc((size_t)(NBK + 1) * 4);
    unsigned int* ebuf = (unsigned int*)alloc((size_t)NE * 4);
    int2*  epair    = (int2*)alloc((size_t)NE * 8);
    unsigned short* Wt = (unsigned short*)alloc((size_t)2 * 64 * 192 * 2);
    float* denom    = (float*)alloc(256);

    // init (also zeroes gbcnt/bcur/absorbed/denom)
    k_init_h<<<(NN * 16 + 255) / 256, 256, 0, stream>>>(x, (const float4*)emb, hHa,
                                                        gbcnt, bcur, absorbed, denom);
    k_pe<<<(KK * 16 + 255) / 256, 256, 0, stream>>>(order, hHa, absorbed);

    // bucketed CSR build + weight transpose
    k_bcnt<<<256, 256, 0, stream>>>(dstp, gbcnt);
    k_makeWt<<<96, 256, 0, stream>>>(bases[0], root[0], bases[1], root[1], Wt);
    k_bscan<<<1, 512, 0, stream>>>(gbcnt, bbase);
    k_bplace<<<256, 256, 0, stream>>>(srcp, dstp, et, bbase, bcur, ebuf);
    k_bsort<<<NBK, 256, 0, stream>>>(ebuf, bbase, epair, rowstart);

    int glayer = (NN + 63) / 64;

    // layer 0: hHa -> hHb ; layer 1: hHb -> hHa
    k_layer<<<glayer, 256, 0, stream>>>(rowstart, epair, comp[0], hHa, Wt, bias[0], hHb);
    k_layer<<<glayer, 256, 0, stream>>>(rowstart, epair, comp[1], hHb, Wt + (size_t)64 * 192,
                                        bias[1], hHa);

    // layer 2: hHa -> h2 (W2 built in-kernel; gather fused with exp-reduce)
    k_gemm2<<<(NN + 255) / 256, 256, 0, stream>>>(hHa, bases[2], comp[2], root[2], bias[2], xW2, h2);
    k_gather2<<<(NN + 255) / 256, 256, 0, stream>>>(rowstart, epair, xW2, h2, absorbed, denom);

    k_final<<<(NN + 255) / 256, 256, 0, stream>>>(h2, absorbed, denom, (float*)d_out);
}

// Round 15
// 175.746 us; speedup vs baseline: 2.1266x; 1.1869x over previous
//
#include <hip/hip_runtime.h>
#include <hip/hip_fp16.h>
#include <math.h>

#define NN 100000
#define NE 1600000
#define RR 5
#define HH 64
#define KK 10000
#define NBB 2
#define NBK 391            // dst buckets of 256 nodes
#define EPB 6250           // edges per block in bucket passes (256 blocks)
#define BSLOT 4608         // padded slots per bucket (mean 4096 + 8 sigma)
#define MPITCH 136         // LDS mix row pitch in halves

typedef _Float16 f16x8 __attribute__((ext_vector_type(8)));
typedef float f32x4 __attribute__((ext_vector_type(4)));

// ---------------- h init: hH[n] = fp16(emb[x[n]]) + zero scratch ----------------
__global__ void k_init_h(const int* __restrict__ x, const float4* __restrict__ emb4,
                         unsigned short* __restrict__ hH, int* __restrict__ bcur,
                         int* __restrict__ absorbed, float* __restrict__ denom) {
    int idx = blockIdx.x * blockDim.x + threadIdx.x;
    if (idx >= NN * 16) return;
    int n = idx >> 4;
    int q = idx & 15;
    float4 v = emb4[x[n] * 16 + q];
    __half2 lo = __floats2half2_rn(v.x, v.y);
    __half2 hi = __floats2half2_rn(v.z, v.w);
    *(uint2*)&hH[(size_t)n * HH + q * 4] = make_uint2(*(unsigned*)&lo, *(unsigned*)&hi);
    if (idx < NBK) bcur[idx] = 0;
    if (idx == NBK) denom[0] = 0.f;
    if (idx < NN) absorbed[idx] = 0;
}

// ---------------- PE add + absorbed mask ----------------
__global__ void k_pe(const int* __restrict__ order, unsigned short* __restrict__ hH,
                     int* __restrict__ absorbed) {
    int idx = blockIdx.x * blockDim.x + threadIdx.x;
    if (idx >= KK * 16) return;
    int t = idx >> 4;
    int q = idx & 15;
    int node = order[t];
    float v = (float)sin((double)(t + 1));   // exact arg reduction, matches np
    uint2 u = *(uint2*)&hH[(size_t)node * HH + q * 4];
    float2 lo = __half22float2(*(__half2*)&u.x);
    float2 hi = __half22float2(*(__half2*)&u.y);
    __half2 nlo = __floats2half2_rn(lo.x + v, lo.y + v);
    __half2 nhi = __floats2half2_rn(hi.x + v, hi.y + v);
    *(uint2*)&hH[(size_t)node * HH + q * 4] = make_uint2(*(unsigned*)&nlo, *(unsigned*)&nhi);
    if (q == 0) absorbed[node] = 1;
}

// ---------------- bucket place: LDS histogram + span reservation + packed scatter ----------------
// ebuf entry = (dst&255)<<20 | src<<3 | rel ; bucket b occupies [b*BSLOT, b*BSLOT+cnt)
__global__ void k_bplace(const int* __restrict__ src, const int* __restrict__ dst,
                         const int* __restrict__ et, int* __restrict__ bcur,
                         unsigned int* __restrict__ ebuf) {
    __shared__ int hist[NBK];
    __shared__ int lbase[NBK];
    __shared__ int lcur[NBK];
    int tid = threadIdx.x;
    for (int i = tid; i < NBK; i += 256) { hist[i] = 0; lcur[i] = 0; }
    __syncthreads();
    int e0 = blockIdx.x * EPB;
    int e1 = e0 + EPB < NE ? e0 + EPB : NE;
    for (int e = e0 + tid; e < e1; e += 256)
        atomicAdd(&hist[dst[e] >> 8], 1);
    __syncthreads();
    for (int i = tid; i < NBK; i += 256)
        if (hist[i]) lbase[i] = i * BSLOT + atomicAdd(&bcur[i], hist[i]);
    __syncthreads();
    for (int e = e0 + tid; e < e1; e += 256) {
        int d = dst[e];
        int b = d >> 8;
        int r = atomicAdd(&lcur[b], 1);
        int idx = lbase[b] + r;
        if (idx < (b + 1) * BSLOT)
            ebuf[idx] = ((unsigned)(d & 255) << 20) | ((unsigned)src[e] << 3) | (unsigned)et[e];
    }
}

// ---------------- bucket sort: per-dst grouping + cnt -> epair(4B), rowse, norm5g ----------------
// epair entry = cnt<<23 | src<<3 | rel
__launch_bounds__(256)
__global__ void k_bsort(const unsigned int* __restrict__ ebuf, const int* __restrict__ bcur,
                        unsigned int* __restrict__ epair, int2* __restrict__ rowse,
                        float* __restrict__ norm5g) {
    __shared__ unsigned int el[BSLOT];
    __shared__ int cnt5[256 * RR];
    __shared__ int dcur[256];
    __shared__ int s[256];
    int tid = threadIdx.x;
    int b = blockIdx.x;
    int base = b * BSLOT;
    int sz = bcur[b];
    if (sz > BSLOT) sz = BSLOT;

    for (int i = tid; i < sz; i += 256) el[i] = ebuf[base + i];
    for (int i = tid; i < 256 * RR; i += 256) cnt5[i] = 0;
    __syncthreads();
    for (int i = tid; i < sz; i += 256) {
        unsigned int e = el[i];
        atomicAdd(&cnt5[(e >> 20) * RR + (e & 7)], 1);
    }
    __syncthreads();
    int deg = 0;
#pragma unroll
    for (int r = 0; r < RR; r++) deg += cnt5[tid * RR + r];
    s[tid] = deg;
    dcur[tid] = 0;
    __syncthreads();
#pragma unroll
    for (int off = 1; off < 256; off <<= 1) {
        int t = (tid >= off) ? s[tid - off] : 0;
        __syncthreads();
        s[tid] += t;
        __syncthreads();
    }
    int rs = s[tid] - deg;      // exclusive within bucket
    int d = b * 256 + tid;
    if (d < NN) {
        rowse[d] = make_int2(base + rs, base + rs + deg);
#pragma unroll
        for (int r = 0; r < RR; r++) {
            int c = cnt5[tid * RR + r];
            norm5g[(size_t)d * RR + r] = 1.0f / (float)(c > 1 ? c : 1);
        }
    }
    __syncthreads();
    for (int i = tid; i < sz; i += 256) {
        unsigned int e = el[i];
        int d8 = e >> 20;
        int rk = atomicAdd(&dcur[d8], 1);
        int pos = base + (s[d8] - (cnt5[d8 * RR + 0] + cnt5[d8 * RR + 1] + cnt5[d8 * RR + 2]
                                   + cnt5[d8 * RR + 3] + cnt5[d8 * RR + 4])) + rk;
        unsigned int cnt = (unsigned)cnt5[d8 * RR + (e & 7)];
        epair[pos] = (cnt << 23) | (e & 0xFFFFFu);
    }
}

// ---------------- Wt build: fp16 W^T for layers 0/1: Wt[layer][o][k], k in [0,192) ----------------
__global__ void k_makeWt(const float* __restrict__ b0, const float* __restrict__ r0,
                         const float* __restrict__ b1, const float* __restrict__ r1,
                         unsigned short* __restrict__ Wt) {
    int idx = blockIdx.x * 256 + threadIdx.x;
    if (idx >= 2 * 64 * 192) return;
    int layer = idx / (64 * 192);
    int rem = idx - layer * 64 * 192;
    int o = rem / 192, k = rem - o * 192;
    const float* bases = layer ? b1 : b0;
    const float* root  = layer ? r1 : r0;
    float w = (k < 64)  ? bases[(size_t)k * HH + o]
            : (k < 128) ? bases[(size_t)HH * HH + (size_t)(k - 64) * HH + o]
                        : root[(size_t)(k - 128) * HH + o];
    __half hv = __float2half_rn(w);
    Wt[idx] = *(unsigned short*)&hv;
}

// ---------------- fused layer: 8-chain x8-unroll gather into LDS, then MFMA GEMM ----------------
// Phase 1: 8-lane group per node; per-dst weight LUT wlutS[row][r] = comp[r]*norm5(dst,r)
// (rel 5..7 = zero weight; guard entry = 5). Phase 2: MFMA 16x16x32_f16, K=192.
// DO2: fused layer-2 GEMV epilogue (sW2 dots via 16-lane shfl butterfly) -> xW2, h2.
template <int DO2>
__launch_bounds__(256)
__global__ void k_layer(const int2* __restrict__ rowse, const unsigned int* __restrict__ epair,
                        const float* __restrict__ norm5g, const float* __restrict__ comp,
                        const unsigned short* __restrict__ hH, const unsigned short* __restrict__ Wt,
                        const float* __restrict__ bias, unsigned short* __restrict__ outH,
                        const float* __restrict__ bases2, const float* __restrict__ comp2,
                        const float* __restrict__ root2, const float* __restrict__ bias2,
                        float* __restrict__ xW2, float* __restrict__ h2) {
    __shared__ float2 lut[8];
    __shared__ float2 wlutS[64][8];
    __shared__ _Float16 mixs[64][MPITCH];
    __shared__ float sW2[6 * HH];
    int tid = threadIdx.x;
    int wave = tid >> 6;
    int lane = tid & 63;
    if (tid < 8) {
        int r = tid < RR ? tid : 0;
        lut[tid] = make_float2(comp[r * NBB + 0], comp[r * NBB + 1]);
    }
    if (DO2) {
        for (int i2 = tid; i2 < 6 * HH; i2 += 256) {
            int c = i2 >> 6, k = i2 & 63;
            sW2[i2] = (c < RR) ? (comp2[c * NBB + 0] * bases2[k] + comp2[c * NBB + 1] * bases2[HH + k])
                               : root2[k];
        }
    }
    __syncthreads();

    int n0 = blockIdx.x * 64;
    int g  = lane >> 3;          // node subgroup 0..7
    int dq = lane & 7;           // dim octet: dims [dq*8, dq*8+8)

    // ---- phase 1: 8 nodes per wave concurrently, 8-edge batches ----
    for (int i = 0; i < 2; ++i) {
        int row = wave * 16 + i * 8 + g;
        int node = n0 + row;
        float m0[8] = {}, m1[8] = {};
        int beg = 0, end = 0;
        if (node < NN) { int2 se = rowse[node]; beg = se.x; end = se.y; }
        // per-node weight LUT: wlutS[row][r] = comp[r]*norm ; r>=5 -> 0
        float nv = (dq < RR && node < NN) ? norm5g[(size_t)node * RR + dq] : 0.f;
        float2 cw = (dq < RR) ? make_float2(lut[dq].x * nv, lut[dq].y * nv)
                              : make_float2(0.f, 0.f);
        wlutS[row][dq] = cw;

        unsigned int p[8];
#pragma unroll
        for (int u = 0; u < 8; ++u) p[u] = (beg + u < end) ? epair[beg + u] : 5u;
        for (int j = beg; j < end; j += 8) {
            unsigned int q[8];
#pragma unroll
            for (int u = 0; u < 8; ++u)
                q[u] = (j + 8 + u < end) ? epair[j + 8 + u] : 5u;
            uint4 ua[8];
#pragma unroll
            for (int u = 0; u < 8; ++u)
                ua[u] = *(const uint4*)&hH[(size_t)((p[u] >> 3) & 0x1FFFFu) * HH + dq * 8];
#pragma unroll
            for (int u = 0; u < 8; ++u) {
                float2 cc = wlutS[row][p[u] & 7];
                float a0 = cc.x, a1 = cc.y;
                float2 f;
                f = __half22float2(*(__half2*)&ua[u].x);
                m0[0] += a0 * f.x; m0[1] += a0 * f.y; m1[0] += a1 * f.x; m1[1] += a1 * f.y;
                f = __half22float2(*(__half2*)&ua[u].y);
                m0[2] += a0 * f.x; m0[3] += a0 * f.y; m1[2] += a1 * f.x; m1[3] += a1 * f.y;
                f = __half22float2(*(__half2*)&ua[u].z);
                m0[4] += a0 * f.x; m0[5] += a0 * f.y; m1[4] += a1 * f.x; m1[5] += a1 * f.y;
                f = __half22float2(*(__half2*)&ua[u].w);
                m0[6] += a0 * f.x; m0[7] += a0 * f.y; m1[6] += a1 * f.x; m1[7] += a1 * f.y;
            }
#pragma unroll
            for (int u = 0; u < 8; ++u) p[u] = q[u];
        }
        __half2 a01 = __floats2half2_rn(m0[0], m0[1]);
        __half2 a23 = __floats2half2_rn(m0[2], m0[3]);
        __half2 a45 = __floats2half2_rn(m0[4], m0[5]);
        __half2 a67 = __floats2half2_rn(m0[6], m0[7]);
        *(uint4*)&mixs[row][dq * 8] =
            make_uint4(*(unsigned*)&a01, *(unsigned*)&a23, *(unsigned*)&a45, *(unsigned*)&a67);
        __half2 b01 = __floats2half2_rn(m1[0], m1[1]);
        __half2 b23 = __floats2half2_rn(m1[2], m1[3]);
        __half2 b45 = __floats2half2_rn(m1[4], m1[5]);
        __half2 b67 = __floats2half2_rn(m1[6], m1[7]);
        *(uint4*)&mixs[row][64 + dq * 8] =
            make_uint4(*(unsigned*)&b01, *(unsigned*)&b23, *(unsigned*)&b45, *(unsigned*)&b67);
    }
    // no barrier: phase 2 A-frags read only this wave's mixs rows

    // ---- phase 2: MFMA ----
    int lm = lane & 15;
    int lk = (lane >> 4) * 8;
    int rowA = wave * 16 + lm;
    int nodeA = n0 + rowA;
    int nodeClamp = nodeA < NN ? nodeA : NN - 1;

    f32x4 acc0 = {}, acc1 = {}, acc2 = {}, acc3 = {};
#pragma unroll
    for (int ks = 0; ks < 6; ++ks) {
        f16x8 a;
        if (ks < 4) a = *(const f16x8*)&mixs[rowA][ks * 32 + lk];
        else        a = *(const f16x8*)&hH[(size_t)nodeClamp * HH + (ks - 4) * 32 + lk];
        f16x8 b0 = *(const f16x8*)&Wt[(size_t)(0 * 16 + lm) * 192 + ks * 32 + lk];
        f16x8 b1 = *(const f16x8*)&Wt[(size_t)(1 * 16 + lm) * 192 + ks * 32 + lk];
        f16x8 b2 = *(const f16x8*)&Wt[(size_t)(2 * 16 + lm) * 192 + ks * 32 + lk];
        f16x8 b3 = *(const f16x8*)&Wt[(size_t)(3 * 16 + lm) * 192 + ks * 32 + lk];
        acc0 = __builtin_amdgcn_mfma_f32_16x16x32_f16(a, b0, acc0, 0, 0, 0);
        acc1 = __builtin_amdgcn_mfma_f32_16x16x32_f16(a, b1, acc1, 0, 0, 0);
        acc2 = __builtin_amdgcn_mfma_f32_16x16x32_f16(a, b2, acc2, 0, 0, 0);
        acc3 = __builtin_amdgcn_mfma_f32_16x16x32_f16(a, b3, acc3, 0, 0, 0);
    }

    float bv0 = bias[0 * 16 + lm];
    float bv1 = bias[1 * 16 + lm];
    float bv2 = bias[2 * 16 + lm];
    float bv3 = bias[3 * 16 + lm];

    int nrow = n0 + wave * 16 + (lane >> 4) * 4;
#pragma unroll
    for (int j = 0; j < 4; ++j) {
        int node = nrow + j;
        float v0 = acc0[j] + bv0;
        float v1 = acc1[j] + bv1;
        float v2 = acc2[j] + bv2;
        float v3 = acc3[j] + bv3;
        if (node < NN) {
            __half h0 = __float2half_rn(v0), h1 = __float2half_rn(v1);
            __half h2v = __float2half_rn(v2), h3 = __float2half_rn(v3);
            outH[(size_t)node * HH +  0 + lm] = *(unsigned short*)&h0;
            outH[(size_t)node * HH + 16 + lm] = *(unsigned short*)&h1;
            outH[(size_t)node * HH + 32 + lm] = *(unsigned short*)&h2v;
            outH[(size_t)node * HH + 48 + lm] = *(unsigned short*)&h3;
        }
        if (DO2) {
            // fused layer-2 GEMV: 6 dots over dims {lm, lm+16, lm+32, lm+48} x 16 lanes
            float p0 = v0 * sW2[0 * HH + lm] + v1 * sW2[0 * HH + 16 + lm]
                     + v2 * sW2[0 * HH + 32 + lm] + v3 * sW2[0 * HH + 48 + lm];
            float p1 = v0 * sW2[1 * HH + lm] + v1 * sW2[1 * HH + 16 + lm]
                     + v2 * sW2[1 * HH + 32 + lm] + v3 * sW2[1 * HH + 48 + lm];
            float p2 = v0 * sW2[2 * HH + lm] + v1 * sW2[2 * HH + 16 + lm]
                     + v2 * sW2[2 * HH + 32 + lm] + v3 * sW2[2 * HH + 48 + lm];
            float p3 = v0 * sW2[3 * HH + lm] + v1 * sW2[3 * HH + 16 + lm]
                     + v2 * sW2[3 * HH + 32 + lm] + v3 * sW2[3 * HH + 48 + lm];
            float p4 = v0 * sW2[4 * HH + lm] + v1 * sW2[4 * HH + 16 + lm]
                     + v2 * sW2[4 * HH + 32 + lm] + v3 * sW2[4 * HH + 48 + lm];
            float p5 = v0 * sW2[5 * HH + lm] + v1 * sW2[5 * HH + 16 + lm]
                     + v2 * sW2[5 * HH + 32 + lm] + v3 * sW2[5 * HH + 48 + lm];
#pragma unroll
            for (int off = 1; off < 16; off <<= 1) {
                p0 += __shfl_xor(p0, off); p1 += __shfl_xor(p1, off);
                p2 += __shfl_xor(p2, off); p3 += __shfl_xor(p3, off);
                p4 += __shfl_xor(p4, off); p5 += __shfl_xor(p5, off);
            }
            if (lm == 0 && node < NN) {
                xW2[(size_t)node * RR + 0] = p0;
                xW2[(size_t)node * RR + 1] = p1;
                xW2[(size_t)node * RR + 2] = p2;
                xW2[(size_t)node * RR + 3] = p3;
                xW2[(size_t)node * RR + 4] = p4;
                h2[node] = p5 + bias2[0];
            }
        }
    }
}

// ---------------- layer-2 gather + fused masked exp-sum ----------------
__global__ void k_gather2(const int2* __restrict__ rowse, const unsigned int* __restrict__ epair,
                          const float* __restrict__ xW2, float* __restrict__ h2,
                          const int* __restrict__ absorbed, float* __restrict__ denom) {
    __shared__ float sdata[256];
    int tid = threadIdx.x;
    int n = blockIdx.x * blockDim.x + tid;
    float local = 0.f;
    if (n < NN) {
        int2 se = rowse[n];
        float acc = h2[n];
        for (int j = se.x; j < se.y; ++j) {
            unsigned int e = epair[j];
            int c = e >> 23;
            float nv = 1.0f / (float)(c > 1 ? c : 1);
            acc += nv * xW2[(size_t)((e >> 3) & 0x1FFFFu) * RR + (e & 7)];
        }
        h2[n] = acc;
        if (!absorbed[n]) local = expf(acc);
    }
    sdata[tid] = local;
    __syncthreads();
    for (int s = 128; s > 0; s >>= 1) {
        if (tid < s) sdata[tid] += sdata[tid + s];
        __syncthreads();
    }
    if (tid == 0) atomicAdd(denom, sdata[0]);
}

// ---------------- final normalize ----------------
__global__ void k_final(const float* __restrict__ h2, const int* __restrict__ absorbed,
                        const float* __restrict__ denom, float* __restrict__ out) {
    int n = blockIdx.x * blockDim.x + threadIdx.x;
    if (n >= NN) return;
    out[n] = absorbed[n] ? 0.f : expf(h2[n]) / denom[0];
}

extern "C" void kernel_launch(void* const* d_in, const int* in_sizes, int n_in,
                              void* d_out, int out_size, void* d_ws, size_t ws_size,
                              hipStream_t stream) {
    const int* x     = (const int*)d_in[0];
    const int* ei    = (const int*)d_in[1];
    const int* et    = (const int*)d_in[2];
    const int* order = (const int*)d_in[3];
    const float* emb = (const float*)d_in[4];
    const float* bases[3] = {(const float*)d_in[5], (const float*)d_in[9],  (const float*)d_in[13]};
    const float* comp[3]  = {(const float*)d_in[6], (const float*)d_in[10], (const float*)d_in[14]};
    const float* root[3]  = {(const float*)d_in[7], (const float*)d_in[11], (const float*)d_in[15]};
    const float* bias[3]  = {(const float*)d_in[8], (const float*)d_in[12], (const float*)d_in[16]};
    const int* srcp = ei;
    const int* dstp = ei + NE;

    char* w = (char*)d_ws;
    size_t off = 0;
    auto alloc = [&](size_t bytes) -> void* {
        void* p = w + off;
        off = (off + bytes + 255) & ~(size_t)255;
        return p;
    };
    unsigned short* hHa = (unsigned short*)alloc((size_t)NN * HH * 2);
    unsigned short* hHb = (unsigned short*)alloc((size_t)NN * HH * 2);
    float* xW2      = (float*)alloc((size_t)NN * RR * 4);
    float* h2       = (float*)alloc((size_t)NN * 4);
    int*   absorbed = (int*)alloc((size_t)NN * 4);
    int2*  rowse    = (int2*)alloc((size_t)NN * 8);
    float* norm5g   = (float*)alloc((size_t)NN * RR * 4);
    int*   bcur     = (int*)alloc((size_t)NBK * 4);
    unsigned int* ebuf  = (unsigned int*)alloc((size_t)NBK * BSLOT * 4);
    unsigned int* epair = (unsigned int*)alloc((size_t)NBK * BSLOT * 4);
    unsigned short* Wt  = (unsigned short*)alloc((size_t)2 * 64 * 192 * 2);
    float* denom    = (float*)alloc(256);

    // init (also zeroes bcur/absorbed/denom)
    k_init_h<<<(NN * 16 + 255) / 256, 256, 0, stream>>>(x, (const float4*)emb, hHa,
                                                        bcur, absorbed, denom);
    k_pe<<<(KK * 16 + 255) / 256, 256, 0, stream>>>(order, hHa, absorbed);

    // CSR build (padded buckets: no count/scan passes) + weight transpose
    k_makeWt<<<96, 256, 0, stream>>>(bases[0], root[0], bases[1], root[1], Wt);
    k_bplace<<<256, 256, 0, stream>>>(srcp, dstp, et, bcur, ebuf);
    k_bsort<<<NBK, 256, 0, stream>>>(ebuf, bcur, epair, rowse, norm5g);

    int glayer = (NN + 63) / 64;

    // layer 0: hHa -> hHb
    k_layer<0><<<glayer, 256, 0, stream>>>(rowse, epair, norm5g, comp[0], hHa, Wt, bias[0], hHb,
                                           nullptr, nullptr, nullptr, nullptr, nullptr, nullptr);
    // layer 1: hHb -> hHa, with fused layer-2 GEMV epilogue -> xW2, h2
    k_layer<1><<<glayer, 256, 0, stream>>>(rowse, epair, norm5g, comp[1], hHb,
                                           Wt + (size_t)64 * 192, bias[1], hHa,
                                           bases[2], comp[2], root[2], bias[2], xW2, h2);

    // layer 2 aggregation + masked exp-sum, then normalize
    k_gather2<<<(NN + 255) / 256, 256, 0, stream>>>(rowse, epair, xW2, h2, absorbed, denom);
    k_final<<<(NN + 255) / 256, 256, 0, stream>>>(h2, absorbed, denom, (float*)d_out);
}